// Round 6
// baseline (897.600 us; speedup 1.0000x reference)
//
#include <hip/hip_runtime.h>
#include <math.h>

#define T_  4
#define B_  8
#define C1  128
#define C2  256
#define H_  128
#define W_  128
#define BN_EPS 1e-5f

// ---- workspace layout (identical to round 4) ----
// sp: packed spikes uint8 [B][131 rows][130 pix][128 ci], bits0-3 = t0..t3,
//     byte offset within pixel block swizzled: c ^ ((pix&7)<<4)
#define SP_BSTR  2179840ull              // 131*130*128
#define SP_SIZE  17438720ull             // 8 * SP_BSTR
#define AZ0_OFF  SP_SIZE                 // 16coblk*9tap*2cq*1024 i8 digit0
#define AZ_SIZE  294912ull
#define AZ1_OFF  (AZ0_OFF + AZ_SIZE)
#define AR0_OFF  (AZ1_OFF + AZ_SIZE)     // 16coblk*2cq*1024
#define AR_SIZE  32768ull
#define AR1_OFF  (AR0_OFF + AR_SIZE)
#define PRM_OFF  (AR1_OFF + AR_SIZE)     // 1024 f32: zmul|zoff|rmul|roff

// ---- main-kernel LDS (27392 B -> 3+ blocks/CU) ----
#define RING_ROW 8448                    // 66 pix * 128 B
#define LDS_RING 0                       // 3 * 8448 = 25344
#define LDS_STG  25344                   // 2t * 16co * 16dw * 4B = 2048
#define LDS_TOT  27392

typedef __attribute__((ext_vector_type(4))) int i32x4;

#define MFI8(acc, A, Bv) acc = __builtin_amdgcn_mfma_i32_16x16x64_i8(A, Bv, acc, 0, 0, 0)

__global__ __launch_bounds__(256) void zero_ws_kernel(uint4* __restrict__ p, int n16) {
    int i = blockIdx.x * 256 + threadIdx.x;
    int stride = gridDim.x * 256;
    for (; i < n16; i += stride) p[i] = make_uint4(0u, 0u, 0u, 0u);
}

// Quantize weights to per-co 15-bit fixed point, split into 2 signed i8 digits,
// packed in MFMA A-fragment order (k = cq*64 + q*16 + j). Blocks 0-255: z (w1),
// blocks 256-511: r (wr). Also writes folded BN params.
__global__ __launch_bounds__(256) void prep_kernel(
    const float* __restrict__ w1, const float* __restrict__ wr,
    const float* __restrict__ g1, const float* __restrict__ v1,
    const float* __restrict__ b1, const float* __restrict__ m1,
    const float* __restrict__ gr, const float* __restrict__ vr,
    const float* __restrict__ br, const float* __restrict__ mr,
    unsigned char* __restrict__ ws)
{
    __shared__ float red[256];
    const int tid = threadIdx.x;
    const bool is_r = blockIdx.x >= 256;
    const int co = blockIdx.x & 255;
    const int n = is_r ? 128 : 1152;
    const float* wsrc = is_r ? (wr + co * 128) : (w1 + co * 1152);

    float mx = 0.0f;
    for (int i = tid; i < n; i += 256) mx = fmaxf(mx, fabsf(wsrc[i]));
    red[tid] = mx;
    __syncthreads();
    for (int s = 128; s > 0; s >>= 1) {
        if (tid < s) red[tid] = fmaxf(red[tid], red[tid + s]);
        __syncthreads();
    }
    const float scale = red[0];
    const float qs = 32638.0f / scale;

    char* d0p = (char*)(ws + (is_r ? AR0_OFF : AZ0_OFF));
    char* d1p = (char*)(ws + (is_r ? AR1_OFF : AZ1_OFF));
    for (int i = tid; i < n; i += 256) {
        const int wq = __float2int_rn(wsrc[i] * qs);
        const int d1 = ((wq + 128) & 255) - 128;
        const int d0 = (wq - d1) >> 8;
        int ci, tap;
        if (is_r) { ci = i; tap = 0; } else { ci = i / 9; tap = i - ci * 9; }
        const int cq = ci >> 6, qq = (ci >> 4) & 3, jj = ci & 15;
        const int addr = is_r
            ? ((co >> 4) * 2048 + cq * 1024 + qq * 256 + (co & 15) * 16 + jj)
            : ((co >> 4) * 18432 + (tap * 2 + cq) * 1024 + qq * 256 + (co & 15) * 16 + jj);
        d0p[addr] = (char)d0;
        d1p[addr] = (char)d1;
    }
    if (tid == 0) {
        float* prm = (float*)(ws + PRM_OFF);
        if (!is_r) {
            const float s1 = g1[co] * (1.0f / sqrtf(v1[co] + BN_EPS));
            prm[co] = (scale / 32638.0f) * s1;
            prm[256 + co] = b1[co] - m1[co] * s1;
        } else {
            const float s2 = gr[co] * (1.0f / sqrtf(vr[co] + BN_EPS));
            prm[512 + co] = (scale / 32638.0f) * s2;
            prm[768 + co] = br[co] - mr[co] * s2;
        }
    }
}

// Stem: conv3x3 (2->128) + BN + LIF, writes packed (byte-swizzled) spikes.
__global__ __launch_bounds__(256) void stem_kernel(
    const float* __restrict__ x, const float* __restrict__ w0,
    const float* __restrict__ g0, const float* __restrict__ b0,
    const float* __restrict__ m0, const float* __restrict__ v0,
    unsigned char* __restrict__ sp)
{
    const int wseg = blockIdx.x;
    const int h    = blockIdx.y;
    const int b    = blockIdx.z;
    const int lane = threadIdx.x & 63;
    const int cg   = threadIdx.x >> 6;
    const int w    = wseg * 64 + lane;

    __shared__ float wl[2304];
    __shared__ float sc0s[128], m0s[128], b0s[128];

    for (int i = threadIdx.x; i < 2304; i += 256) wl[i] = w0[i];
    if (threadIdx.x < 128) {
        const int c = threadIdx.x;
        sc0s[c] = g0[c] * (1.0f / sqrtf(v0[c] + BN_EPS));
        m0s[c] = m0[c]; b0s[c] = b0[c];
    }
    __syncthreads();

    float xv[4][2][3][3];
#pragma unroll
    for (int t = 0; t < 4; ++t)
#pragma unroll
        for (int ci = 0; ci < 2; ++ci)
#pragma unroll
            for (int dh = 0; dh < 3; ++dh)
#pragma unroll
                for (int dw = 0; dw < 3; ++dw) {
                    const int hh = h + dh - 1, ww = w + dw - 1;
                    const bool ok = ((unsigned)hh < 128u) && ((unsigned)ww < 128u);
                    xv[t][ci][dh][dw] = ok ? x[(((size_t)(t * 8 + b) * 2 + ci) * 128 + hh) * 128 + ww] : 0.0f;
                }

    const int pix = w + 1;
    const int sw = (pix & 7) << 4;
    unsigned char* dst = sp + ((size_t)b * SP_BSTR) + ((size_t)((h + 1) * 130 + pix)) * 128;
    for (int i = 0; i < 8; ++i) {
        unsigned dwv = 0u;
#pragma unroll
        for (int j = 0; j < 4; ++j) {
            const int c = cg * 32 + i * 4 + j;
            float wreg[18];
#pragma unroll
            for (int k = 0; k < 18; ++k) wreg[k] = wl[c * 18 + k];
            const float sc = sc0s[c], mm = m0s[c], bb = b0s[c];
            float v = 0.0f; unsigned bits = 0u;
#pragma unroll
            for (int t = 0; t < 4; ++t) {
                float sum = 0.0f;
#pragma unroll
                for (int ci = 0; ci < 2; ++ci)
#pragma unroll
                    for (int dh = 0; dh < 3; ++dh)
#pragma unroll
                        for (int dw = 0; dw < 3; ++dw)
                            sum += xv[t][ci][dh][dw] * wreg[ci * 9 + dh * 3 + dw];
                const float y = (sum - mm) * sc + bb;
                v = v + (y - v) * 0.5f;
                if (v - 1.0f >= 0.0f) { bits |= 1u << t; v = 0.0f; }
            }
            dwv |= bits << (j * 8);
        }
        *(unsigned*)(dst + ((cg * 32 + i * 4) ^ sw)) = dwv;
    }
}

// Main fused: conv3x3(z) + conv1x1(r) via mfma_i32_16x16x64_i8 (2 digits),
// BN + LIF in-lane, out = z_spike + r_spike with full-line staged stores.
// Block = 4 waves = 16 co x 64 pix x 1 row x 4 t per pass, 8 passes.
// Grid: 4096 blocks, XCD-swizzled so all 16 coblk of a spike strip share an XCD.
__global__ __launch_bounds__(256, 3) void main_i8(
    const unsigned char* __restrict__ ws, float* __restrict__ out)
{
    __shared__ __align__(16) char lds[LDS_TOT];

    const int bid = blockIdx.x;
    const int xcd = bid & 7;
    const int i0  = bid >> 3;            // 0..511
    const int coblk = i0 & 15;
    const int jj  = i0 >> 4;             // 0..31
    const int hwb = jj * 8 + xcd;        // 0..255
    const int hstrip = hwb >> 4;         // 0..15
    const int wseg   = (hwb >> 3) & 1;
    const int b      = hwb & 7;

    const int tid  = threadIdx.x;
    const int lane = tid & 63;
    const int wid  = tid >> 6;
    const int q    = lane >> 4;
    const int r16  = lane & 15;
    const int r3   = r16 & 3;
    const int ra   = r16 >> 2;
    const int wbase  = wseg * 64;
    const int hfirst = hstrip * 8;

    const unsigned char* spg = ws + (size_t)b * SP_BSTR + (size_t)wbase * 128;
    const char* Az0 = (const char*)(ws + AZ0_OFF) + coblk * 18432 + lane * 16;
    const char* Az1 = (const char*)(ws + AZ1_OFF) + coblk * 18432 + lane * 16;
    const char* Ar0 = (const char*)(ws + AR0_OFF) + coblk * 2048 + lane * 16;
    const char* Ar1 = (const char*)(ws + AR1_OFF) + coblk * 2048 + lane * 16;

    // folded epilogue params per acc register (co = coblk*16 + q*4 + reg)
    const float* prm = (const float*)(ws + PRM_OFF);
    float zmul_[4], zoff_[4], rmul_[4], roff_[4];
#pragma unroll
    for (int reg = 0; reg < 4; ++reg) {
        const int co = coblk * 16 + q * 4 + reg;
        zmul_[reg] = prm[co];       zoff_[reg] = prm[256 + co];
        rmul_[reg] = prm[512 + co]; roff_[reg] = prm[768 + co];
    }

    // ring init: sp rows hfirst..hfirst+2 (66-pix slice) -> slot gr%3
    for (int i = tid; i < 1584; i += 256) {
        const int rr = i / 528;
        const int off = (i - rr * 528) * 16;
        const int gr = hfirst + rr;
        *(uint4*)&lds[LDS_RING + (gr % 3) * RING_ROW + off] =
            *(const uint4*)(spg + (size_t)gr * 16640 + off);
    }
    __syncthreads();

    const unsigned M1 = 0x01010101u;
    const int plbase = wid * 16 + r16;   // local output pixel
    const int co16 = q * 4 + r3;
    const int pq = wid * 4 + ra;
    const int stg0 = LDS_STG + (co16 * 16 + (pq ^ ((co16 & 7) << 1))) * 4;

    for (int p = 0; p < 8; ++p) {
        const int h0 = hfirst + p;

        // prefetch next sp row slice (gr = h0+3) into registers
        uint4 pf0, pf1, pf2;
        if (p < 7) {
            const unsigned char* src = spg + (size_t)(h0 + 3) * 16640;
            pf0 = *(const uint4*)(src + tid * 16);
            pf1 = *(const uint4*)(src + (tid + 256) * 16);
            if (tid < 16) pf2 = *(const uint4*)(src + (tid + 512) * 16);
        }

        const int sl0 = h0 % 3;
        const int sl1 = (h0 + 1) % 3;
        const int sl2 = (h0 + 2) % 3;
        const int rbase[3] = { LDS_RING + sl0 * RING_ROW,
                               LDS_RING + sl1 * RING_ROW,
                               LDS_RING + sl2 * RING_ROW };

        i32x4 z0[4], z1[4], r0a[4], r1a[4];
#pragma unroll
        for (int t = 0; t < 4; ++t) {
            z0[t] = (i32x4)(0); z1[t] = (i32x4)(0);
            r0a[t] = (i32x4)(0); r1a[t] = (i32x4)(0);
        }

#pragma unroll
        for (int cq = 0; cq < 2; ++cq) {
#pragma unroll
            for (int kw = 0; kw < 3; ++kw) {
                i32x4 a0[3], a1[3];
#pragma unroll
                for (int kh = 0; kh < 3; ++kh) {
                    const int fb = ((kh * 3 + kw) * 2 + cq) * 1024;
                    a0[kh] = *(const i32x4*)(Az0 + fb);
                    a1[kh] = *(const i32x4*)(Az1 + fb);
                }
                i32x4 c0, c1;
                if (kw == 1) {
                    c0 = *(const i32x4*)(Ar0 + cq * 1024);
                    c1 = *(const i32x4*)(Ar1 + cq * 1024);
                }
                const int pl = plbase + kw;
                const int addrb = pl * 128 + ((cq * 64 + q * 16) ^ ((pl & 7) << 4));
#pragma unroll
                for (int rr = 0; rr < 3; ++rr) {
                    const uint4 d = *(const uint4*)&lds[rbase[rr] + addrb];
#pragma unroll
                    for (int t = 0; t < 4; ++t) {
                        i32x4 bt;
                        bt[0] = (int)((d.x >> t) & M1);
                        bt[1] = (int)((d.y >> t) & M1);
                        bt[2] = (int)((d.z >> t) & M1);
                        bt[3] = (int)((d.w >> t) & M1);
                        MFI8(z0[t], a0[rr], bt);
                        MFI8(z1[t], a1[rr], bt);
                        if (kw == 1 && rr == 1) {
                            MFI8(r0a[t], c0, bt);
                            MFI8(r1a[t], c1, bt);
                        }
                    }
                }
            }
        }

        // Epilogue: combine digits, BN + LIF (in-lane t-series), byte-pack
        unsigned pack[4] = {0u, 0u, 0u, 0u};
#pragma unroll
        for (int reg = 0; reg < 4; ++reg) {
            float vz = 0.0f, vr2 = 0.0f;
#pragma unroll
            for (int t = 0; t < 4; ++t) {
                const int zi = z0[t][reg] * 256 + z1[t][reg];
                const float yz = fmaf((float)zi, zmul_[reg], zoff_[reg]);
                vz = vz + (yz - vz) * 0.5f;
                unsigned val = 0u;
                if (vz - 1.0f >= 0.0f) { val = 1u; vz = 0.0f; }
                const int ri = r0a[t][reg] * 256 + r1a[t][reg];
                const float yr = fmaf((float)ri, rmul_[reg], roff_[reg]);
                vr2 = vr2 + (yr - vr2) * 0.5f;
                if (vr2 - 1.0f >= 0.0f) { val += 1u; vr2 = 0.0f; }
                pack[t] |= val << (reg * 8);
            }
        }

        // in-wave 4x4 byte transpose across r3 lanes: co-major -> pixel-major
#pragma unroll
        for (int t = 0; t < 4; ++t) {
            unsigned u = pack[t];
            unsigned pt = __shfl_xor(u, 1);
            u = (r3 & 1) ? ((u & 0xFF00FF00u) | ((pt >> 8) & 0x00FF00FFu))
                         : ((u & 0x00FF00FFu) | ((pt << 8) & 0xFF00FF00u));
            pt = __shfl_xor(u, 2);
            u = (r3 & 2) ? ((u & 0xFFFF0000u) | (pt >> 16))
                         : ((u & 0x0000FFFFu) | (pt << 16));
            pack[t] = u;
        }

        __syncthreads();   // bar1: ring reads + previous stage reads done

        if (p < 7) {       // commit prefetched row into retired slot sl0
            char* dst = &lds[LDS_RING + sl0 * RING_ROW];
            *(uint4*)(dst + tid * 16) = pf0;
            *(uint4*)(dst + (tid + 256) * 16) = pf1;
            if (tid < 16) *(uint4*)(dst + (tid + 512) * 16) = pf2;
        }
        // stage phase A (t0, t1)
        *(unsigned*)&lds[stg0] = pack[0];
        *(unsigned*)&lds[stg0 + 1024] = pack[1];
        __syncthreads();   // bar2

#pragma unroll
        for (int ph = 0; ph < 2; ++ph) {
            // cooperative full-line stores: 512 units = 2t x 16co x 16 pix-quads
#pragma unroll
            for (int uu = 0; uu < 2; ++uu) {
                const int u = tid + uu * 256;
                const int tt = u >> 8;
                const int c16 = (u >> 4) & 15;
                const int quad = u & 15;
                const unsigned dv = *(const unsigned*)
                    &lds[LDS_STG + ((tt * 16 + c16) * 16 + (quad ^ ((c16 & 7) << 1))) * 4];
                float4 f;
                f.x = (float)(dv & 0xffu);
                f.y = (float)((dv >> 8) & 0xffu);
                f.z = (float)((dv >> 16) & 0xffu);
                f.w = (float)((dv >> 24) & 0xffu);
                const int t = ph * 2 + tt;
                const int co = coblk * 16 + c16;
                float* op = out + (((size_t)(t * 8 + b) * 256 + co) << 14)
                                + h0 * 128 + wbase + quad * 4;
                *(float4*)op = f;
            }
            if (ph == 0) {
                __syncthreads();   // bar3: phase-A reads done
                *(unsigned*)&lds[stg0] = pack[2];
                *(unsigned*)&lds[stg0 + 1024] = pack[3];
                __syncthreads();   // bar4: phase-B staged
            }
        }
    }
}

extern "C" void kernel_launch(void* const* d_in, const int* in_sizes, int n_in,
                              void* d_out, int out_size, void* d_ws, size_t ws_size,
                              hipStream_t stream) {
    const float* x  = (const float*)d_in[0];
    const float* w0 = (const float*)d_in[1];
    const float* g0 = (const float*)d_in[2];
    const float* b0 = (const float*)d_in[3];
    const float* m0 = (const float*)d_in[4];
    const float* v0 = (const float*)d_in[5];
    const float* w1 = (const float*)d_in[6];
    const float* g1 = (const float*)d_in[7];
    const float* b1 = (const float*)d_in[8];
    const float* m1 = (const float*)d_in[9];
    const float* v1 = (const float*)d_in[10];
    const float* wr = (const float*)d_in[11];
    const float* gr = (const float*)d_in[12];
    const float* br = (const float*)d_in[13];
    const float* mr = (const float*)d_in[14];
    const float* vr = (const float*)d_in[15];

    unsigned char* ws = (unsigned char*)d_ws;
    const int n16 = (int)(SP_SIZE / 16);

    zero_ws_kernel<<<dim3(2048), dim3(256), 0, stream>>>((uint4*)ws, n16);
    prep_kernel<<<dim3(512), dim3(256), 0, stream>>>(w1, wr, g1, v1, b1, m1, gr, vr, br, mr, ws);
    stem_kernel<<<dim3(2, 128, 8), dim3(256), 0, stream>>>(x, w0, g0, b0, m0, v0, ws);
    main_i8<<<dim3(4096), dim3(256), 0, stream>>>(ws, (float*)d_out);
}

// Round 7
// 693.716 us; speedup vs baseline: 1.2939x; 1.2939x over previous
//
#include <hip/hip_runtime.h>
#include <math.h>

#define T_  4
#define B_  8
#define C1  128
#define C2  256
#define H_  128
#define W_  128
#define BN_EPS 1e-5f

// ---- workspace layout (identical to round 4) ----
// sp: packed spikes uint8 [B][131 rows][130 pix][128 ci], bits0-3 = t0..t3,
//     byte offset within pixel block swizzled: c ^ ((pix&7)<<4)
#define SP_BSTR  2179840ull              // 131*130*128
#define SP_SIZE  17438720ull             // 8 * SP_BSTR
#define AZ0_OFF  SP_SIZE                 // 16coblk*9tap*2cq*1024 i8 digit0
#define AZ_SIZE  294912ull
#define AZ1_OFF  (AZ0_OFF + AZ_SIZE)
#define AR0_OFF  (AZ1_OFF + AZ_SIZE)     // 16coblk*2cq*1024
#define AR_SIZE  32768ull
#define AR1_OFF  (AR0_OFF + AR_SIZE)
#define PRM_OFF  (AR1_OFF + AR_SIZE)     // 1024 f32: zmul|zoff|rmul|roff

// ---- main-kernel LDS (76544 B -> 2 blocks/CU) ----
#define LDS_AZ1  0                       // 18432
#define LDS_RING 18432                   // 3 * 16640 = 49920
#define LDS_STG  68352                   // 4t * 16co * 32quad * 4B = 8192
#define LDS_TOT  76544

typedef __attribute__((ext_vector_type(4))) int i32x4;
typedef __attribute__((ext_vector_type(4))) float f32x4;

#define MFI8(acc, A, Bv) acc = __builtin_amdgcn_mfma_i32_16x16x64_i8(A, Bv, acc, 0, 0, 0)

__global__ __launch_bounds__(256) void zero_ws_kernel(uint4* __restrict__ p, int n16) {
    int i = blockIdx.x * 256 + threadIdx.x;
    int stride = gridDim.x * 256;
    for (; i < n16; i += stride) p[i] = make_uint4(0u, 0u, 0u, 0u);
}

// Quantize weights to per-co 15-bit fixed point, split into 2 signed i8 digits,
// packed in MFMA A-fragment order (k = cq*64 + q*16 + j). Blocks 0-255: z (w1),
// blocks 256-511: r (wr). Also writes folded BN params.
__global__ __launch_bounds__(256) void prep_kernel(
    const float* __restrict__ w1, const float* __restrict__ wr,
    const float* __restrict__ g1, const float* __restrict__ v1,
    const float* __restrict__ b1, const float* __restrict__ m1,
    const float* __restrict__ gr, const float* __restrict__ vr,
    const float* __restrict__ br, const float* __restrict__ mr,
    unsigned char* __restrict__ ws)
{
    __shared__ float red[256];
    const int tid = threadIdx.x;
    const bool is_r = blockIdx.x >= 256;
    const int co = blockIdx.x & 255;
    const int n = is_r ? 128 : 1152;
    const float* wsrc = is_r ? (wr + co * 128) : (w1 + co * 1152);

    float mx = 0.0f;
    for (int i = tid; i < n; i += 256) mx = fmaxf(mx, fabsf(wsrc[i]));
    red[tid] = mx;
    __syncthreads();
    for (int s = 128; s > 0; s >>= 1) {
        if (tid < s) red[tid] = fmaxf(red[tid], red[tid + s]);
        __syncthreads();
    }
    const float scale = red[0];
    const float qs = 32638.0f / scale;

    char* d0p = (char*)(ws + (is_r ? AR0_OFF : AZ0_OFF));
    char* d1p = (char*)(ws + (is_r ? AR1_OFF : AZ1_OFF));
    for (int i = tid; i < n; i += 256) {
        const int wq = __float2int_rn(wsrc[i] * qs);
        const int d1 = ((wq + 128) & 255) - 128;
        const int d0 = (wq - d1) >> 8;
        int ci, tap;
        if (is_r) { ci = i; tap = 0; } else { ci = i / 9; tap = i - ci * 9; }
        const int cq = ci >> 6, qq = (ci >> 4) & 3, jj = ci & 15;
        const int addr = is_r
            ? ((co >> 4) * 2048 + cq * 1024 + qq * 256 + (co & 15) * 16 + jj)
            : ((co >> 4) * 18432 + (tap * 2 + cq) * 1024 + qq * 256 + (co & 15) * 16 + jj);
        d0p[addr] = (char)d0;
        d1p[addr] = (char)d1;
    }
    if (tid == 0) {
        float* prm = (float*)(ws + PRM_OFF);
        if (!is_r) {
            const float s1 = g1[co] * (1.0f / sqrtf(v1[co] + BN_EPS));
            prm[co] = (scale / 32638.0f) * s1;
            prm[256 + co] = b1[co] - m1[co] * s1;
        } else {
            const float s2 = gr[co] * (1.0f / sqrtf(vr[co] + BN_EPS));
            prm[512 + co] = (scale / 32638.0f) * s2;
            prm[768 + co] = br[co] - mr[co] * s2;
        }
    }
}

// Stem: conv3x3 (2->128) + BN + LIF, writes packed (byte-swizzled) spikes.
__global__ __launch_bounds__(256) void stem_kernel(
    const float* __restrict__ x, const float* __restrict__ w0,
    const float* __restrict__ g0, const float* __restrict__ b0,
    const float* __restrict__ m0, const float* __restrict__ v0,
    unsigned char* __restrict__ sp)
{
    const int wseg = blockIdx.x;
    const int h    = blockIdx.y;
    const int b    = blockIdx.z;
    const int lane = threadIdx.x & 63;
    const int cg   = threadIdx.x >> 6;
    const int w    = wseg * 64 + lane;

    __shared__ float wl[2304];
    __shared__ float sc0s[128], m0s[128], b0s[128];

    for (int i = threadIdx.x; i < 2304; i += 256) wl[i] = w0[i];
    if (threadIdx.x < 128) {
        const int c = threadIdx.x;
        sc0s[c] = g0[c] * (1.0f / sqrtf(v0[c] + BN_EPS));
        m0s[c] = m0[c]; b0s[c] = b0[c];
    }
    __syncthreads();

    float xv[4][2][3][3];
#pragma unroll
    for (int t = 0; t < 4; ++t)
#pragma unroll
        for (int ci = 0; ci < 2; ++ci)
#pragma unroll
            for (int dh = 0; dh < 3; ++dh)
#pragma unroll
                for (int dw = 0; dw < 3; ++dw) {
                    const int hh = h + dh - 1, ww = w + dw - 1;
                    const bool ok = ((unsigned)hh < 128u) && ((unsigned)ww < 128u);
                    xv[t][ci][dh][dw] = ok ? x[(((size_t)(t * 8 + b) * 2 + ci) * 128 + hh) * 128 + ww] : 0.0f;
                }

    const int pix = w + 1;
    const int sw = (pix & 7) << 4;
    unsigned char* dst = sp + ((size_t)b * SP_BSTR) + ((size_t)((h + 1) * 130 + pix)) * 128;
    for (int i = 0; i < 8; ++i) {
        unsigned dwv = 0u;
#pragma unroll
        for (int j = 0; j < 4; ++j) {
            const int c = cg * 32 + i * 4 + j;
            float wreg[18];
#pragma unroll
            for (int k = 0; k < 18; ++k) wreg[k] = wl[c * 18 + k];
            const float sc = sc0s[c], mm = m0s[c], bb = b0s[c];
            float v = 0.0f; unsigned bits = 0u;
#pragma unroll
            for (int t = 0; t < 4; ++t) {
                float sum = 0.0f;
#pragma unroll
                for (int ci = 0; ci < 2; ++ci)
#pragma unroll
                    for (int dh = 0; dh < 3; ++dh)
#pragma unroll
                        for (int dw = 0; dw < 3; ++dw)
                            sum += xv[t][ci][dh][dw] * wreg[ci * 9 + dh * 3 + dw];
                const float y = (sum - mm) * sc + bb;
                v = v + (y - v) * 0.5f;
                if (v - 1.0f >= 0.0f) { bits |= 1u << t; v = 0.0f; }
            }
            dwv |= bits << (j * 8);
        }
        *(unsigned*)(dst + ((cg * 32 + i * 4) ^ sw)) = dwv;
    }
}

// Main fused: conv3x3(z) + conv1x1(r) via mfma_i32_16x16x64_i8 (2 digits),
// BN + LIF in-lane, out = z_spike + r_spike via full-row nontemporal stores.
// Block = 4 waves, 16 co x 128 pix x 1 row x 4 t per pass (two sequential
// 64-pix nf sub-tiles), 8 passes. Az digit0 + Ar in registers, Az digit1 in
// LDS (staged once). Grid 2048, XCD-swizzled (16 coblk share a spike strip).
__global__ __launch_bounds__(256, 2) void main_i8(
    const unsigned char* __restrict__ ws, float* __restrict__ out)
{
    __shared__ __align__(16) char lds[LDS_TOT];

    const int bid = blockIdx.x;
    const int xcd = bid & 7;
    const int i0  = bid >> 3;            // 0..255
    const int coblk = i0 & 15;
    const int jj  = i0 >> 4;             // 0..15
    const int strip = jj * 8 + xcd;      // 0..127
    const int hstrip = strip >> 3;
    const int b      = strip & 7;

    const int tid  = threadIdx.x;
    const int lane = tid & 63;
    const int wid  = tid >> 6;
    const int q    = lane >> 4;
    const int r16  = lane & 15;
    const int r3   = r16 & 3;
    const int ra   = r16 >> 2;
    const int hfirst = hstrip * 8;

    const unsigned char* spg = ws + (size_t)b * SP_BSTR;

    // ---- weights: Az digit0 + Ar (both digits) into registers, once ----
    i32x4 a0z[2][9];
#pragma unroll
    for (int cq = 0; cq < 2; ++cq)
#pragma unroll
        for (int tap = 0; tap < 9; ++tap)
            a0z[cq][tap] = *(const i32x4*)(ws + AZ0_OFF + coblk * 18432
                                           + ((tap * 2 + cq) << 10) + lane * 16);
    i32x4 ar0[2], ar1[2];
#pragma unroll
    for (int cq = 0; cq < 2; ++cq) {
        ar0[cq] = *(const i32x4*)(ws + AR0_OFF + coblk * 2048 + (cq << 10) + lane * 16);
        ar1[cq] = *(const i32x4*)(ws + AR1_OFF + coblk * 2048 + (cq << 10) + lane * 16);
    }

    // folded epilogue params per acc register (co = coblk*16 + q*4 + reg)
    const float* prm = (const float*)(ws + PRM_OFF);
    float zmul_[4], zoff_[4], rmul_[4], roff_[4];
#pragma unroll
    for (int reg = 0; reg < 4; ++reg) {
        const int co = coblk * 16 + q * 4 + reg;
        zmul_[reg] = prm[co];       zoff_[reg] = prm[256 + co];
        rmul_[reg] = prm[512 + co]; roff_[reg] = prm[768 + co];
    }

    // ---- stage Az digit1 (18 KB) + ring rows hfirst..hfirst+2 ----
    {
        const uint4* s = (const uint4*)(ws + AZ1_OFF + (size_t)coblk * 18432);
        uint4* d = (uint4*)&lds[LDS_AZ1];
        for (int i = tid; i < 1152; i += 256) d[i] = s[i];
    }
    for (int i = tid; i < 3120; i += 256) {
        const int rr = i / 1040;
        const int off = (i - rr * 1040) * 16;
        const int gr = hfirst + rr;
        *(uint4*)&lds[LDS_RING + (gr % 3) * 16640 + off] =
            *(const uint4*)(spg + (size_t)gr * 16640 + off);
    }
    __syncthreads();

    const unsigned M1 = 0x01010101u;

    auto reduce_nf = [&](const int nf, const int h0, unsigned* po) {
        const int plb = wid * 32 + nf * 16 + r16;
        i32x4 z0[4], z1[4], r0a[4], r1a[4];
#pragma unroll
        for (int t = 0; t < 4; ++t) {
            z0[t] = (i32x4)(0); z1[t] = (i32x4)(0);
            r0a[t] = (i32x4)(0); r1a[t] = (i32x4)(0);
        }
#pragma unroll
        for (int cq = 0; cq < 2; ++cq) {
#pragma unroll
            for (int kw = 0; kw < 3; ++kw) {
                i32x4 a1[3];
#pragma unroll
                for (int kh = 0; kh < 3; ++kh)
                    a1[kh] = *(const i32x4*)&lds[LDS_AZ1 + (((kh * 3 + kw) * 2 + cq) << 10)
                                                 + lane * 16];
                const int pl = plb + kw;
                const int addrb = pl * 128 + ((cq * 64 + q * 16) ^ ((pl & 7) << 4));
#pragma unroll
                for (int rr = 0; rr < 3; ++rr) {
                    const int slot = (h0 + rr) % 3;
                    const uint4 dd = *(const uint4*)&lds[LDS_RING + slot * 16640 + addrb];
#pragma unroll
                    for (int t = 0; t < 4; ++t) {
                        i32x4 bt;
                        bt[0] = (int)((dd.x >> t) & M1);
                        bt[1] = (int)((dd.y >> t) & M1);
                        bt[2] = (int)((dd.z >> t) & M1);
                        bt[3] = (int)((dd.w >> t) & M1);
                        MFI8(z0[t], a0z[cq][rr * 3 + kw], bt);
                        MFI8(z1[t], a1[rr], bt);
                        if (kw == 1 && rr == 1) {
                            MFI8(r0a[t], ar0[cq], bt);
                            MFI8(r1a[t], ar1[cq], bt);
                        }
                    }
                }
            }
        }
        // combine digits, BN + LIF (in-lane t-series), byte-pack
        unsigned pack[4] = {0u, 0u, 0u, 0u};
#pragma unroll
        for (int reg = 0; reg < 4; ++reg) {
            float vz = 0.0f, vr2 = 0.0f;
#pragma unroll
            for (int t = 0; t < 4; ++t) {
                const int zi = z0[t][reg] * 256 + z1[t][reg];
                const float yz = fmaf((float)zi, zmul_[reg], zoff_[reg]);
                vz = vz + (yz - vz) * 0.5f;
                unsigned val = 0u;
                if (vz - 1.0f >= 0.0f) { val = 1u; vz = 0.0f; }
                const int ri = r0a[t][reg] * 256 + r1a[t][reg];
                const float yr = fmaf((float)ri, rmul_[reg], roff_[reg]);
                vr2 = vr2 + (yr - vr2) * 0.5f;
                if (vr2 - 1.0f >= 0.0f) { val += 1u; vr2 = 0.0f; }
                pack[t] |= val << (reg * 8);
            }
        }
        // in-wave 4x4 byte transpose across r3 lanes: co-major -> pixel-major
#pragma unroll
        for (int t = 0; t < 4; ++t) {
            unsigned u = pack[t];
            unsigned pt = __shfl_xor(u, 1);
            u = (r3 & 1) ? ((u & 0xFF00FF00u) | ((pt >> 8) & 0x00FF00FFu))
                         : ((u & 0x00FF00FFu) | ((pt << 8) & 0xFF00FF00u));
            pt = __shfl_xor(u, 2);
            u = (r3 & 2) ? ((u & 0xFFFF0000u) | (pt >> 16))
                         : ((u & 0x0000FFFFu) | (pt << 16));
            po[t] = u;
        }
    };

    const int co16 = q * 4 + r3;
    const int swz  = (co16 & 7) << 2;
    const int pq0  = wid * 8 + ra;
    const int pq1  = wid * 8 + 4 + ra;

    for (int p = 0; p < 8; ++p) {
        const int h0 = hfirst + p;

        // prefetch next sp row (gr = h0+3) into registers
        uint4 pf0, pf1, pf2, pf3, pf4;
        if (p < 7) {
            const unsigned char* src = spg + (size_t)(h0 + 3) * 16640;
            pf0 = *(const uint4*)(src + tid * 16);
            pf1 = *(const uint4*)(src + tid * 16 + 4096);
            pf2 = *(const uint4*)(src + tid * 16 + 8192);
            pf3 = *(const uint4*)(src + tid * 16 + 12288);
            if (tid < 16) pf4 = *(const uint4*)(src + tid * 16 + 16384);
        }

        unsigned po0[4], po1[4];
        reduce_nf(0, h0, po0);
        reduce_nf(1, h0, po1);

        __syncthreads();   // bar1: ring + stg reads of previous pass done

        if (p < 7) {       // commit prefetched row into retired slot h0%3
            char* dst = &lds[LDS_RING + (h0 % 3) * 16640];
            *(uint4*)(dst + tid * 16) = pf0;
            *(uint4*)(dst + tid * 16 + 4096) = pf1;
            *(uint4*)(dst + tid * 16 + 8192) = pf2;
            *(uint4*)(dst + tid * 16 + 12288) = pf3;
            if (tid < 16) *(uint4*)(dst + tid * 16 + 16384) = pf4;
        }
#pragma unroll
        for (int t = 0; t < 4; ++t) {
            *(unsigned*)&lds[LDS_STG + ((t * 16 + co16) * 32 + (pq0 ^ swz)) * 4] = po0[t];
            *(unsigned*)&lds[LDS_STG + ((t * 16 + co16) * 32 + (pq1 ^ swz)) * 4] = po1[t];
        }
        __syncthreads();   // bar2: staged bytes + new ring row visible

        // full-row nontemporal stores: 32 lanes x 16 B = 512 B per (t,co) row
#pragma unroll
        for (int it = 0; it < 8; ++it) {
            const int u = it * 256 + tid;
            const int quad = u & 31;
            const int cs   = (u >> 5) & 15;
            const int tt   = u >> 9;
            const unsigned dv = *(const unsigned*)
                &lds[LDS_STG + ((tt * 16 + cs) * 32 + (quad ^ ((cs & 7) << 2))) * 4];
            f32x4 f;
            f[0] = (float)(dv & 0xffu);
            f[1] = (float)((dv >> 8) & 0xffu);
            f[2] = (float)((dv >> 16) & 0xffu);
            f[3] = (float)((dv >> 24) & 0xffu);
            float* op = out + (((size_t)(tt * 8 + b) * 256 + coblk * 16 + cs) << 14)
                            + h0 * 128 + quad * 4;
            __builtin_nontemporal_store(f, (f32x4*)op);
        }
    }
}

extern "C" void kernel_launch(void* const* d_in, const int* in_sizes, int n_in,
                              void* d_out, int out_size, void* d_ws, size_t ws_size,
                              hipStream_t stream) {
    const float* x  = (const float*)d_in[0];
    const float* w0 = (const float*)d_in[1];
    const float* g0 = (const float*)d_in[2];
    const float* b0 = (const float*)d_in[3];
    const float* m0 = (const float*)d_in[4];
    const float* v0 = (const float*)d_in[5];
    const float* w1 = (const float*)d_in[6];
    const float* g1 = (const float*)d_in[7];
    const float* b1 = (const float*)d_in[8];
    const float* m1 = (const float*)d_in[9];
    const float* v1 = (const float*)d_in[10];
    const float* wr = (const float*)d_in[11];
    const float* gr = (const float*)d_in[12];
    const float* br = (const float*)d_in[13];
    const float* mr = (const float*)d_in[14];
    const float* vr = (const float*)d_in[15];

    unsigned char* ws = (unsigned char*)d_ws;
    const int n16 = (int)(SP_SIZE / 16);

    zero_ws_kernel<<<dim3(2048), dim3(256), 0, stream>>>((uint4*)ws, n16);
    prep_kernel<<<dim3(512), dim3(256), 0, stream>>>(w1, wr, g1, v1, b1, m1, gr, vr, br, mr, ws);
    stem_kernel<<<dim3(2, 128, 8), dim3(256), 0, stream>>>(x, w0, g0, b0, m0, v0, ws);
    main_i8<<<dim3(2048), dim3(256), 0, stream>>>(ws, (float*)d_out);
}

// Round 8
// 619.823 us; speedup vs baseline: 1.4482x; 1.1192x over previous
//
#include <hip/hip_runtime.h>
#include <math.h>

#define T_  4
#define B_  8
#define C1  128
#define C2  256
#define H_  128
#define W_  128
#define BN_EPS 1e-5f

// ---- workspace layout (identical to round 4/7) ----
// sp: packed spikes uint8 [B][131 rows][130 pix][128 ci], bits0-3 = t0..t3,
//     byte offset within pixel block swizzled: c ^ ((pix&7)<<4)
#define SP_BSTR  2179840ull              // 131*130*128
#define SP_SIZE  17438720ull             // 8 * SP_BSTR
#define AZ0_OFF  SP_SIZE                 // 16coblk*9tap*2cq*1024 i8 digit0
#define AZ_SIZE  294912ull
#define AZ1_OFF  (AZ0_OFF + AZ_SIZE)
#define AR0_OFF  (AZ1_OFF + AZ_SIZE)     // 16coblk*2cq*1024
#define AR_SIZE  32768ull
#define AR1_OFF  (AR0_OFF + AR_SIZE)
#define PRM_OFF  (AR1_OFF + AR_SIZE)     // 1024 f32: zmul|zoff|rmul|roff

// ---- main-kernel LDS (47872 B -> 3 blocks/CU) ----
#define RING_ROW 8448                    // 66 pix * 128 B
#define LDS_AZ1  0                       // 18432
#define LDS_RING 18432                   // 3 * 8448 = 25344
#define LDS_STG  43776                   // 4t * 16co * 16dw * 4B = 4096
#define LDS_TOT  47872

typedef __attribute__((ext_vector_type(4))) int i32x4;
typedef __attribute__((ext_vector_type(4))) float f32x4;

#define MFI8(acc, A, Bv) acc = __builtin_amdgcn_mfma_i32_16x16x64_i8(A, Bv, acc, 0, 0, 0)

__global__ __launch_bounds__(256) void zero_ws_kernel(uint4* __restrict__ p, int n16) {
    int i = blockIdx.x * 256 + threadIdx.x;
    int stride = gridDim.x * 256;
    for (; i < n16; i += stride) p[i] = make_uint4(0u, 0u, 0u, 0u);
}

// Quantize weights to per-co 15-bit fixed point, split into 2 signed i8 digits,
// packed in MFMA A-fragment order (k = cq*64 + q*16 + j). Blocks 0-255: z (w1),
// blocks 256-511: r (wr). Also writes folded BN params.
__global__ __launch_bounds__(256) void prep_kernel(
    const float* __restrict__ w1, const float* __restrict__ wr,
    const float* __restrict__ g1, const float* __restrict__ v1,
    const float* __restrict__ b1, const float* __restrict__ m1,
    const float* __restrict__ gr, const float* __restrict__ vr,
    const float* __restrict__ br, const float* __restrict__ mr,
    unsigned char* __restrict__ ws)
{
    __shared__ float red[256];
    const int tid = threadIdx.x;
    const bool is_r = blockIdx.x >= 256;
    const int co = blockIdx.x & 255;
    const int n = is_r ? 128 : 1152;
    const float* wsrc = is_r ? (wr + co * 128) : (w1 + co * 1152);

    float mx = 0.0f;
    for (int i = tid; i < n; i += 256) mx = fmaxf(mx, fabsf(wsrc[i]));
    red[tid] = mx;
    __syncthreads();
    for (int s = 128; s > 0; s >>= 1) {
        if (tid < s) red[tid] = fmaxf(red[tid], red[tid + s]);
        __syncthreads();
    }
    const float scale = red[0];
    const float qs = 32638.0f / scale;

    char* d0p = (char*)(ws + (is_r ? AR0_OFF : AZ0_OFF));
    char* d1p = (char*)(ws + (is_r ? AR1_OFF : AZ1_OFF));
    for (int i = tid; i < n; i += 256) {
        const int wq = __float2int_rn(wsrc[i] * qs);
        const int d1 = ((wq + 128) & 255) - 128;
        const int d0 = (wq - d1) >> 8;
        int ci, tap;
        if (is_r) { ci = i; tap = 0; } else { ci = i / 9; tap = i - ci * 9; }
        const int cq = ci >> 6, qq = (ci >> 4) & 3, jj = ci & 15;
        const int addr = is_r
            ? ((co >> 4) * 2048 + cq * 1024 + qq * 256 + (co & 15) * 16 + jj)
            : ((co >> 4) * 18432 + (tap * 2 + cq) * 1024 + qq * 256 + (co & 15) * 16 + jj);
        d0p[addr] = (char)d0;
        d1p[addr] = (char)d1;
    }
    if (tid == 0) {
        float* prm = (float*)(ws + PRM_OFF);
        if (!is_r) {
            const float s1 = g1[co] * (1.0f / sqrtf(v1[co] + BN_EPS));
            prm[co] = (scale / 32638.0f) * s1;
            prm[256 + co] = b1[co] - m1[co] * s1;
        } else {
            const float s2 = gr[co] * (1.0f / sqrtf(vr[co] + BN_EPS));
            prm[512 + co] = (scale / 32638.0f) * s2;
            prm[768 + co] = br[co] - mr[co] * s2;
        }
    }
}

// Stem: conv3x3 (2->128) + BN + LIF, writes packed (byte-swizzled) spikes.
__global__ __launch_bounds__(256) void stem_kernel(
    const float* __restrict__ x, const float* __restrict__ w0,
    const float* __restrict__ g0, const float* __restrict__ b0,
    const float* __restrict__ m0, const float* __restrict__ v0,
    unsigned char* __restrict__ sp)
{
    const int wseg = blockIdx.x;
    const int h    = blockIdx.y;
    const int b    = blockIdx.z;
    const int lane = threadIdx.x & 63;
    const int cg   = threadIdx.x >> 6;
    const int w    = wseg * 64 + lane;

    __shared__ float wl[2304];
    __shared__ float sc0s[128], m0s[128], b0s[128];

    for (int i = threadIdx.x; i < 2304; i += 256) wl[i] = w0[i];
    if (threadIdx.x < 128) {
        const int c = threadIdx.x;
        sc0s[c] = g0[c] * (1.0f / sqrtf(v0[c] + BN_EPS));
        m0s[c] = m0[c]; b0s[c] = b0[c];
    }
    __syncthreads();

    float xv[4][2][3][3];
#pragma unroll
    for (int t = 0; t < 4; ++t)
#pragma unroll
        for (int ci = 0; ci < 2; ++ci)
#pragma unroll
            for (int dh = 0; dh < 3; ++dh)
#pragma unroll
                for (int dw = 0; dw < 3; ++dw) {
                    const int hh = h + dh - 1, ww = w + dw - 1;
                    const bool ok = ((unsigned)hh < 128u) && ((unsigned)ww < 128u);
                    xv[t][ci][dh][dw] = ok ? x[(((size_t)(t * 8 + b) * 2 + ci) * 128 + hh) * 128 + ww] : 0.0f;
                }

    const int pix = w + 1;
    const int sw = (pix & 7) << 4;
    unsigned char* dst = sp + ((size_t)b * SP_BSTR) + ((size_t)((h + 1) * 130 + pix)) * 128;
    for (int i = 0; i < 8; ++i) {
        unsigned dwv = 0u;
#pragma unroll
        for (int j = 0; j < 4; ++j) {
            const int c = cg * 32 + i * 4 + j;
            float wreg[18];
#pragma unroll
            for (int k = 0; k < 18; ++k) wreg[k] = wl[c * 18 + k];
            const float sc = sc0s[c], mm = m0s[c], bb = b0s[c];
            float v = 0.0f; unsigned bits = 0u;
#pragma unroll
            for (int t = 0; t < 4; ++t) {
                float sum = 0.0f;
#pragma unroll
                for (int ci = 0; ci < 2; ++ci)
#pragma unroll
                    for (int dh = 0; dh < 3; ++dh)
#pragma unroll
                        for (int dw = 0; dw < 3; ++dw)
                            sum += xv[t][ci][dh][dw] * wreg[ci * 9 + dh * 3 + dw];
                const float y = (sum - mm) * sc + bb;
                v = v + (y - v) * 0.5f;
                if (v - 1.0f >= 0.0f) { bits |= 1u << t; v = 0.0f; }
            }
            dwv |= bits << (j * 8);
        }
        *(unsigned*)(dst + ((cg * 32 + i * 4) ^ sw)) = dwv;
    }
}

// Main fused: conv3x3(z) + conv1x1(r) via mfma_i32_16x16x64_i8 (2 digits),
// BN + LIF in-lane, out = z_spike + r_spike via full-line staged stores.
// Block = 4 waves = 16 co x 64 pix x 1 row x 4 t per pass, 8 passes.
// Az digit0 + Ar in registers, Az digit1 in LDS. LDS 47.9 KB -> 3 blocks/CU.
// Grid 4096, XCD-swizzled (32 blocks of a spike strip share an XCD).
__global__ __launch_bounds__(256, 4) void main_i8(
    const unsigned char* __restrict__ ws, float* __restrict__ out)
{
    __shared__ __align__(16) char lds[LDS_TOT];

    const int bid = blockIdx.x;
    const int xcd = bid & 7;
    const int k   = bid >> 3;            // 0..511
    const int sub = k & 31;              // 0..31
    const int six = k >> 5;              // 0..15
    const int strip = six * 8 + xcd;     // 0..127
    const int coblk = sub >> 1;
    const int wseg  = sub & 1;
    const int hstrip = strip >> 3;
    const int b      = strip & 7;

    const int tid  = threadIdx.x;
    const int lane = tid & 63;
    const int wid  = tid >> 6;
    const int q    = lane >> 4;
    const int r16  = lane & 15;
    const int r3   = r16 & 3;
    const int ra   = r16 >> 2;
    const int wbase  = wseg * 64;
    const int hfirst = hstrip * 8;

    const unsigned char* spg = ws + (size_t)b * SP_BSTR + (size_t)wbase * 128;

    // ---- weights: Az digit0 + Ar (both digits) into registers, once ----
    i32x4 a0z[2][9];
#pragma unroll
    for (int cq = 0; cq < 2; ++cq)
#pragma unroll
        for (int tap = 0; tap < 9; ++tap)
            a0z[cq][tap] = *(const i32x4*)(ws + AZ0_OFF + coblk * 18432
                                           + ((tap * 2 + cq) << 10) + lane * 16);
    i32x4 ar0[2], ar1[2];
#pragma unroll
    for (int cq = 0; cq < 2; ++cq) {
        ar0[cq] = *(const i32x4*)(ws + AR0_OFF + coblk * 2048 + (cq << 10) + lane * 16);
        ar1[cq] = *(const i32x4*)(ws + AR1_OFF + coblk * 2048 + (cq << 10) + lane * 16);
    }

    // folded epilogue params per acc register (co = coblk*16 + q*4 + reg)
    const float* prm = (const float*)(ws + PRM_OFF);
    float zmul_[4], zoff_[4], rmul_[4], roff_[4];
#pragma unroll
    for (int reg = 0; reg < 4; ++reg) {
        const int co = coblk * 16 + q * 4 + reg;
        zmul_[reg] = prm[co];       zoff_[reg] = prm[256 + co];
        rmul_[reg] = prm[512 + co]; roff_[reg] = prm[768 + co];
    }

    // ---- stage Az digit1 (18 KB) + ring rows hfirst..hfirst+2 (66-pix) ----
    {
        const uint4* s = (const uint4*)(ws + AZ1_OFF + (size_t)coblk * 18432);
        uint4* d = (uint4*)&lds[LDS_AZ1];
        for (int i = tid; i < 1152; i += 256) d[i] = s[i];
    }
    for (int i = tid; i < 1584; i += 256) {      // 3 rows * 528 uint4
        const int rr = i / 528;
        const int off = (i - rr * 528) * 16;
        const int gr = hfirst + rr;
        *(uint4*)&lds[LDS_RING + (gr % 3) * RING_ROW + off] =
            *(const uint4*)(spg + (size_t)gr * 16640 + off);
    }
    __syncthreads();

    const unsigned M1 = 0x01010101u;
    const int plbase = wid * 16 + r16;           // local output pixel (0..63)
    const int co16 = q * 4 + r3;
    const int pq   = wid * 4 + ra;
    const int stg0 = LDS_STG + (co16 * 16 + (pq ^ ((co16 & 7) << 1))) * 4;

    for (int p = 0; p < 8; ++p) {
        const int h0 = hfirst + p;

        // prefetch next sp row slice (gr = h0+3) into registers
        uint4 pf0, pf1, pf2;
        if (p < 7) {
            const unsigned char* src = spg + (size_t)(h0 + 3) * 16640;
            pf0 = *(const uint4*)(src + tid * 16);
            pf1 = *(const uint4*)(src + (tid + 256) * 16);
            if (tid < 16) pf2 = *(const uint4*)(src + (tid + 512) * 16);
        }

        i32x4 z0[4], z1[4], r0a[4], r1a[4];
#pragma unroll
        for (int t = 0; t < 4; ++t) {
            z0[t] = (i32x4)(0); z1[t] = (i32x4)(0);
            r0a[t] = (i32x4)(0); r1a[t] = (i32x4)(0);
        }

#pragma unroll
        for (int cq = 0; cq < 2; ++cq) {
#pragma unroll
            for (int kw = 0; kw < 3; ++kw) {
                i32x4 a1[3];
#pragma unroll
                for (int kh = 0; kh < 3; ++kh)
                    a1[kh] = *(const i32x4*)&lds[LDS_AZ1 + (((kh * 3 + kw) * 2 + cq) << 10)
                                                 + lane * 16];
                const int pl = plbase + kw;
                const int addrb = pl * 128 + ((cq * 64 + q * 16) ^ ((pl & 7) << 4));
#pragma unroll
                for (int rr = 0; rr < 3; ++rr) {
                    const int slot = (h0 + rr) % 3;
                    const uint4 dd = *(const uint4*)&lds[LDS_RING + slot * RING_ROW + addrb];
#pragma unroll
                    for (int t = 0; t < 4; ++t) {
                        i32x4 bt;
                        bt[0] = (int)((dd.x >> t) & M1);
                        bt[1] = (int)((dd.y >> t) & M1);
                        bt[2] = (int)((dd.z >> t) & M1);
                        bt[3] = (int)((dd.w >> t) & M1);
                        MFI8(z0[t], a0z[cq][rr * 3 + kw], bt);
                        MFI8(z1[t], a1[rr], bt);
                        if (kw == 1 && rr == 1) {
                            MFI8(r0a[t], ar0[cq], bt);
                            MFI8(r1a[t], ar1[cq], bt);
                        }
                    }
                }
            }
        }

        // Epilogue: combine digits, BN + LIF (in-lane t-series), byte-pack
        unsigned pack[4] = {0u, 0u, 0u, 0u};
#pragma unroll
        for (int reg = 0; reg < 4; ++reg) {
            float vz = 0.0f, vr2 = 0.0f;
#pragma unroll
            for (int t = 0; t < 4; ++t) {
                const int zi = z0[t][reg] * 256 + z1[t][reg];
                const float yz = fmaf((float)zi, zmul_[reg], zoff_[reg]);
                vz = vz + (yz - vz) * 0.5f;
                unsigned val = 0u;
                if (vz - 1.0f >= 0.0f) { val = 1u; vz = 0.0f; }
                const int ri = r0a[t][reg] * 256 + r1a[t][reg];
                const float yr = fmaf((float)ri, rmul_[reg], roff_[reg]);
                vr2 = vr2 + (yr - vr2) * 0.5f;
                if (vr2 - 1.0f >= 0.0f) { val += 1u; vr2 = 0.0f; }
                pack[t] |= val << (reg * 8);
            }
        }

        // in-wave 4x4 byte transpose across r3 lanes: co-major -> pixel-major
#pragma unroll
        for (int t = 0; t < 4; ++t) {
            unsigned u = pack[t];
            unsigned pt = __shfl_xor(u, 1);
            u = (r3 & 1) ? ((u & 0xFF00FF00u) | ((pt >> 8) & 0x00FF00FFu))
                         : ((u & 0x00FF00FFu) | ((pt << 8) & 0xFF00FF00u));
            pt = __shfl_xor(u, 2);
            u = (r3 & 2) ? ((u & 0xFFFF0000u) | (pt >> 16))
                         : ((u & 0x0000FFFFu) | (pt << 16));
            pack[t] = u;
        }

        __syncthreads();   // bar1: ring + stg reads of previous pass done

        if (p < 7) {       // commit prefetched row into retired slot h0%3
            char* dst = &lds[LDS_RING + (h0 % 3) * RING_ROW];
            *(uint4*)(dst + tid * 16) = pf0;
            *(uint4*)(dst + (tid + 256) * 16) = pf1;
            if (tid < 16) *(uint4*)(dst + (tid + 512) * 16) = pf2;
        }
#pragma unroll
        for (int t = 0; t < 4; ++t)
            *(unsigned*)&lds[stg0 + t * 1024] = pack[t];
        __syncthreads();   // bar2: staged bytes + new ring row visible

        // full-line stores: 16 consecutive lanes cover one 256-B row chunk
#pragma unroll
        for (int it = 0; it < 4; ++it) {
            const int u = it * 256 + tid;        // dword index 0..1023
            const int q4 = u & 15;
            const int cs = (u >> 4) & 15;
            const int tt = u >> 8;
            const unsigned dv = *(const unsigned*)
                &lds[LDS_STG + ((tt * 16 + cs) * 16 + (q4 ^ ((cs & 7) << 1))) * 4];
            f32x4 f;
            f[0] = (float)(dv & 0xffu);
            f[1] = (float)((dv >> 8) & 0xffu);
            f[2] = (float)((dv >> 16) & 0xffu);
            f[3] = (float)((dv >> 24) & 0xffu);
            float* op = out + (((size_t)(tt * 8 + b) * 256 + coblk * 16 + cs) << 14)
                            + h0 * 128 + wbase + q4 * 4;
            *(f32x4*)op = f;
        }
    }
}

extern "C" void kernel_launch(void* const* d_in, const int* in_sizes, int n_in,
                              void* d_out, int out_size, void* d_ws, size_t ws_size,
                              hipStream_t stream) {
    const float* x  = (const float*)d_in[0];
    const float* w0 = (const float*)d_in[1];
    const float* g0 = (const float*)d_in[2];
    const float* b0 = (const float*)d_in[3];
    const float* m0 = (const float*)d_in[4];
    const float* v0 = (const float*)d_in[5];
    const float* w1 = (const float*)d_in[6];
    const float* g1 = (const float*)d_in[7];
    const float* b1 = (const float*)d_in[8];
    const float* m1 = (const float*)d_in[9];
    const float* v1 = (const float*)d_in[10];
    const float* wr = (const float*)d_in[11];
    const float* gr = (const float*)d_in[12];
    const float* br = (const float*)d_in[13];
    const float* mr = (const float*)d_in[14];
    const float* vr = (const float*)d_in[15];

    unsigned char* ws = (unsigned char*)d_ws;
    const int n16 = (int)(SP_SIZE / 16);

    zero_ws_kernel<<<dim3(2048), dim3(256), 0, stream>>>((uint4*)ws, n16);
    prep_kernel<<<dim3(512), dim3(256), 0, stream>>>(w1, wr, g1, v1, b1, m1, gr, vr, br, mr, ws);
    stem_kernel<<<dim3(2, 128, 8), dim3(256), 0, stream>>>(x, w0, g0, b0, m0, v0, ws);
    main_i8<<<dim3(4096), dim3(256), 0, stream>>>(ws, (float*)d_out);
}

// Round 9
// 475.897 us; speedup vs baseline: 1.8861x; 1.3024x over previous
//
#include <hip/hip_runtime.h>
#include <math.h>

#define T_  4
#define B_  8
#define C1  128
#define C2  256
#define H_  128
#define W_  128
#define BN_EPS 1e-5f

// ---- workspace layout (identical to rounds 4-8) ----
// sp: packed spikes uint8 [B][131 rows][130 pix][128 ci], bits0-3 = t0..t3,
//     byte offset within pixel block swizzled: c ^ ((pix&7)<<4)
#define SP_BSTR  2179840ull              // 131*130*128
#define SP_SIZE  17438720ull             // 8 * SP_BSTR
#define AZ0_OFF  SP_SIZE                 // 16coblk*9tap*2cq*1024 i8 digit0
#define AZ_SIZE  294912ull
#define AZ1_OFF  (AZ0_OFF + AZ_SIZE)
#define AR0_OFF  (AZ1_OFF + AZ_SIZE)     // 16coblk*2cq*1024
#define AR_SIZE  32768ull
#define AR1_OFF  (AR0_OFF + AR_SIZE)
#define PRM_OFF  (AR1_OFF + AR_SIZE)     // 1024 f32: zmul|zoff|rmul|roff

// ---- main-kernel LDS (60416 B -> 2 blocks/CU = 16 waves/CU) ----
#define RING_ROW 8448                    // 66 pix * 128 B
#define LDS_AZ1  0                       // 18432
#define LDS_RING 18432                   // 4 * 8448 = 33792
#define LDS_STG  52224                   // 2rg * 4t * 16co * 16dw * 4B = 8192
#define LDS_TOT  60416

typedef __attribute__((ext_vector_type(4))) int i32x4;
typedef __attribute__((ext_vector_type(4))) float f32x4;

#define MFI8(acc, A, Bv) acc = __builtin_amdgcn_mfma_i32_16x16x64_i8(A, Bv, acc, 0, 0, 0)

__global__ __launch_bounds__(256) void zero_ws_kernel(uint4* __restrict__ p, int n16) {
    int i = blockIdx.x * 256 + threadIdx.x;
    int stride = gridDim.x * 256;
    for (; i < n16; i += stride) p[i] = make_uint4(0u, 0u, 0u, 0u);
}

// Quantize weights to per-co 15-bit fixed point, split into 2 signed i8 digits,
// packed in MFMA A-fragment order (k = cq*64 + q*16 + j). Blocks 0-255: z (w1),
// blocks 256-511: r (wr). Also writes folded BN params.
__global__ __launch_bounds__(256) void prep_kernel(
    const float* __restrict__ w1, const float* __restrict__ wr,
    const float* __restrict__ g1, const float* __restrict__ v1,
    const float* __restrict__ b1, const float* __restrict__ m1,
    const float* __restrict__ gr, const float* __restrict__ vr,
    const float* __restrict__ br, const float* __restrict__ mr,
    unsigned char* __restrict__ ws)
{
    __shared__ float red[256];
    const int tid = threadIdx.x;
    const bool is_r = blockIdx.x >= 256;
    const int co = blockIdx.x & 255;
    const int n = is_r ? 128 : 1152;
    const float* wsrc = is_r ? (wr + co * 128) : (w1 + co * 1152);

    float mx = 0.0f;
    for (int i = tid; i < n; i += 256) mx = fmaxf(mx, fabsf(wsrc[i]));
    red[tid] = mx;
    __syncthreads();
    for (int s = 128; s > 0; s >>= 1) {
        if (tid < s) red[tid] = fmaxf(red[tid], red[tid + s]);
        __syncthreads();
    }
    const float scale = red[0];
    const float qs = 32638.0f / scale;

    char* d0p = (char*)(ws + (is_r ? AR0_OFF : AZ0_OFF));
    char* d1p = (char*)(ws + (is_r ? AR1_OFF : AZ1_OFF));
    for (int i = tid; i < n; i += 256) {
        const int wq = __float2int_rn(wsrc[i] * qs);
        const int d1 = ((wq + 128) & 255) - 128;
        const int d0 = (wq - d1) >> 8;
        int ci, tap;
        if (is_r) { ci = i; tap = 0; } else { ci = i / 9; tap = i - ci * 9; }
        const int cq = ci >> 6, qq = (ci >> 4) & 3, jj = ci & 15;
        const int addr = is_r
            ? ((co >> 4) * 2048 + cq * 1024 + qq * 256 + (co & 15) * 16 + jj)
            : ((co >> 4) * 18432 + (tap * 2 + cq) * 1024 + qq * 256 + (co & 15) * 16 + jj);
        d0p[addr] = (char)d0;
        d1p[addr] = (char)d1;
    }
    if (tid == 0) {
        float* prm = (float*)(ws + PRM_OFF);
        if (!is_r) {
            const float s1 = g1[co] * (1.0f / sqrtf(v1[co] + BN_EPS));
            prm[co] = (scale / 32638.0f) * s1;
            prm[256 + co] = b1[co] - m1[co] * s1;
        } else {
            const float s2 = gr[co] * (1.0f / sqrtf(vr[co] + BN_EPS));
            prm[512 + co] = (scale / 32638.0f) * s2;
            prm[768 + co] = br[co] - mr[co] * s2;
        }
    }
}

// Stem: conv3x3 (2->128) + BN + LIF, writes packed (byte-swizzled) spikes.
__global__ __launch_bounds__(256) void stem_kernel(
    const float* __restrict__ x, const float* __restrict__ w0,
    const float* __restrict__ g0, const float* __restrict__ b0,
    const float* __restrict__ m0, const float* __restrict__ v0,
    unsigned char* __restrict__ sp)
{
    const int wseg = blockIdx.x;
    const int h    = blockIdx.y;
    const int b    = blockIdx.z;
    const int lane = threadIdx.x & 63;
    const int cg   = threadIdx.x >> 6;
    const int w    = wseg * 64 + lane;

    __shared__ float wl[2304];
    __shared__ float sc0s[128], m0s[128], b0s[128];

    for (int i = threadIdx.x; i < 2304; i += 256) wl[i] = w0[i];
    if (threadIdx.x < 128) {
        const int c = threadIdx.x;
        sc0s[c] = g0[c] * (1.0f / sqrtf(v0[c] + BN_EPS));
        m0s[c] = m0[c]; b0s[c] = b0[c];
    }
    __syncthreads();

    float xv[4][2][3][3];
#pragma unroll
    for (int t = 0; t < 4; ++t)
#pragma unroll
        for (int ci = 0; ci < 2; ++ci)
#pragma unroll
            for (int dh = 0; dh < 3; ++dh)
#pragma unroll
                for (int dw = 0; dw < 3; ++dw) {
                    const int hh = h + dh - 1, ww = w + dw - 1;
                    const bool ok = ((unsigned)hh < 128u) && ((unsigned)ww < 128u);
                    xv[t][ci][dh][dw] = ok ? x[(((size_t)(t * 8 + b) * 2 + ci) * 128 + hh) * 128 + ww] : 0.0f;
                }

    const int pix = w + 1;
    const int sw = (pix & 7) << 4;
    unsigned char* dst = sp + ((size_t)b * SP_BSTR) + ((size_t)((h + 1) * 130 + pix)) * 128;
    for (int i = 0; i < 8; ++i) {
        unsigned dwv = 0u;
#pragma unroll
        for (int j = 0; j < 4; ++j) {
            const int c = cg * 32 + i * 4 + j;
            float wreg[18];
#pragma unroll
            for (int k = 0; k < 18; ++k) wreg[k] = wl[c * 18 + k];
            const float sc = sc0s[c], mm = m0s[c], bb = b0s[c];
            float v = 0.0f; unsigned bits = 0u;
#pragma unroll
            for (int t = 0; t < 4; ++t) {
                float sum = 0.0f;
#pragma unroll
                for (int ci = 0; ci < 2; ++ci)
#pragma unroll
                    for (int dh = 0; dh < 3; ++dh)
#pragma unroll
                        for (int dw = 0; dw < 3; ++dw)
                            sum += xv[t][ci][dh][dw] * wreg[ci * 9 + dh * 3 + dw];
                const float y = (sum - mm) * sc + bb;
                v = v + (y - v) * 0.5f;
                if (v - 1.0f >= 0.0f) { bits |= 1u << t; v = 0.0f; }
            }
            dwv |= bits << (j * 8);
        }
        *(unsigned*)(dst + ((cg * 32 + i * 4) ^ sw)) = dwv;
    }
}

// Main fused: conv3x3(z) + conv1x1(r) via mfma_i32_16x16x64_i8 (2 digits),
// BN + LIF in-lane, out = z_spike + r_spike via full-line staged stores.
// Block = 8 waves (512 thr): waves 0-3 -> row h0, waves 4-7 -> row h0+1.
// 16 co x 64 pix x 2 rows x 4 t per pass, 4 passes (8-row strip).
// Az digit0 + Ar in registers, Az digit1 in LDS; 4-slot spike ring.
// LDS 60.4 KB -> 2 blocks/CU = 16 waves/CU. Grid 4096, XCD-swizzled.
__global__ __launch_bounds__(512, 2) void main_i8_2r(
    const unsigned char* __restrict__ ws, float* __restrict__ out)
{
    __shared__ __align__(16) char lds[LDS_TOT];

    const int bid = blockIdx.x;
    const int xcd = bid & 7;
    const int k   = bid >> 3;            // 0..511
    const int sub = k & 31;              // 0..31
    const int six = k >> 5;              // 0..15
    const int strip = six * 8 + xcd;     // 0..127
    const int coblk = sub >> 1;
    const int wseg  = sub & 1;
    const int hstrip = strip >> 3;
    const int b      = strip & 7;

    const int tid  = threadIdx.x;
    const int lane = tid & 63;
    const int wid  = tid >> 6;           // 0..7
    const int rg   = wid >> 2;           // row group 0/1
    const int ws4  = wid & 3;            // pixel sub-tile 0..3
    const int q    = lane >> 4;
    const int r16  = lane & 15;
    const int r3   = r16 & 3;
    const int ra   = r16 >> 2;
    const int wbase  = wseg * 64;
    const int hfirst = hstrip * 8;

    const unsigned char* spg = ws + (size_t)b * SP_BSTR + (size_t)wbase * 128;

    // ---- weights: Az digit0 + Ar (both digits) into registers, once ----
    i32x4 a0z[2][9];
#pragma unroll
    for (int cq = 0; cq < 2; ++cq)
#pragma unroll
        for (int tap = 0; tap < 9; ++tap)
            a0z[cq][tap] = *(const i32x4*)(ws + AZ0_OFF + coblk * 18432
                                           + ((tap * 2 + cq) << 10) + lane * 16);
    i32x4 ar0[2], ar1[2];
#pragma unroll
    for (int cq = 0; cq < 2; ++cq) {
        ar0[cq] = *(const i32x4*)(ws + AR0_OFF + coblk * 2048 + (cq << 10) + lane * 16);
        ar1[cq] = *(const i32x4*)(ws + AR1_OFF + coblk * 2048 + (cq << 10) + lane * 16);
    }

    // folded epilogue params per acc register (co = coblk*16 + q*4 + reg)
    const float* prm = (const float*)(ws + PRM_OFF);
    float zmul_[4], zoff_[4], rmul_[4], roff_[4];
#pragma unroll
    for (int reg = 0; reg < 4; ++reg) {
        const int co = coblk * 16 + q * 4 + reg;
        zmul_[reg] = prm[co];       zoff_[reg] = prm[256 + co];
        rmul_[reg] = prm[512 + co]; roff_[reg] = prm[768 + co];
    }

    // ---- stage Az digit1 (18 KB) + ring rows hfirst..hfirst+3 (66-pix) ----
    {
        const uint4* s = (const uint4*)(ws + AZ1_OFF + (size_t)coblk * 18432);
        uint4* d = (uint4*)&lds[LDS_AZ1];
        for (int i = tid; i < 1152; i += 512) d[i] = s[i];
    }
    for (int i = tid; i < 2112; i += 512) {      // 4 rows * 528 uint4
        const int rr = i / 528;
        const int off = (i - rr * 528) * 16;
        const int gr = hfirst + rr;
        *(uint4*)&lds[LDS_RING + (gr & 3) * RING_ROW + off] =
            *(const uint4*)(spg + (size_t)gr * 16640 + off);
    }
    __syncthreads();

    const unsigned M1 = 0x01010101u;
    const int plbase = ws4 * 16 + r16;           // local output pixel (0..63)
    const int co16 = q * 4 + r3;
    const int pq   = ws4 * 4 + ra;
    const int swz  = (co16 & 7) << 1;
    const int stg0 = LDS_STG + ((rg * 4 * 16 + co16) * 16 + (pq ^ swz)) * 4;

    for (int p = 0; p < 4; ++p) {
        const int h0 = hfirst + 2 * p;
        const int my_row = h0 + rg;

        // prefetch next 2 sp rows (gr = h0+4, h0+5) into registers
        uint4 pfa0, pfa1, pfb0, pfb1;
        if (p < 3) {
            const unsigned char* s0 = spg + (size_t)(h0 + 4) * 16640;
            const unsigned char* s1 = spg + (size_t)(h0 + 5) * 16640;
            pfa0 = *(const uint4*)(s0 + tid * 16);
            pfb0 = *(const uint4*)(s1 + tid * 16);
            if (tid < 16) {
                pfa1 = *(const uint4*)(s0 + (tid + 512) * 16);
                pfb1 = *(const uint4*)(s1 + (tid + 512) * 16);
            }
        }

        i32x4 z0[4], z1[4], r0a[4], r1a[4];
#pragma unroll
        for (int t = 0; t < 4; ++t) {
            z0[t] = (i32x4)(0); z1[t] = (i32x4)(0);
            r0a[t] = (i32x4)(0); r1a[t] = (i32x4)(0);
        }

#pragma unroll
        for (int cq = 0; cq < 2; ++cq) {
#pragma unroll
            for (int kw = 0; kw < 3; ++kw) {
                i32x4 a1[3];
#pragma unroll
                for (int kh = 0; kh < 3; ++kh)
                    a1[kh] = *(const i32x4*)&lds[LDS_AZ1 + (((kh * 3 + kw) * 2 + cq) << 10)
                                                 + lane * 16];
                const int pl = plbase + kw;
                const int addrb = pl * 128 + ((cq * 64 + q * 16) ^ ((pl & 7) << 4));
#pragma unroll
                for (int rr = 0; rr < 3; ++rr) {
                    const int slot = (my_row + rr) & 3;   // input sp row my_row+rr
                    const uint4 dd = *(const uint4*)&lds[LDS_RING + slot * RING_ROW + addrb];
#pragma unroll
                    for (int t = 0; t < 4; ++t) {
                        i32x4 bt;
                        bt[0] = (int)((dd.x >> t) & M1);
                        bt[1] = (int)((dd.y >> t) & M1);
                        bt[2] = (int)((dd.z >> t) & M1);
                        bt[3] = (int)((dd.w >> t) & M1);
                        MFI8(z0[t], a0z[cq][rr * 3 + kw], bt);
                        MFI8(z1[t], a1[rr], bt);
                        if (kw == 1 && rr == 1) {
                            MFI8(r0a[t], ar0[cq], bt);
                            MFI8(r1a[t], ar1[cq], bt);
                        }
                    }
                }
            }
        }

        // Epilogue: combine digits, BN + LIF (in-lane t-series), byte-pack
        unsigned pack[4] = {0u, 0u, 0u, 0u};
#pragma unroll
        for (int reg = 0; reg < 4; ++reg) {
            float vz = 0.0f, vr2 = 0.0f;
#pragma unroll
            for (int t = 0; t < 4; ++t) {
                const int zi = z0[t][reg] * 256 + z1[t][reg];
                const float yz = fmaf((float)zi, zmul_[reg], zoff_[reg]);
                vz = vz + (yz - vz) * 0.5f;
                unsigned val = 0u;
                if (vz - 1.0f >= 0.0f) { val = 1u; vz = 0.0f; }
                const int ri = r0a[t][reg] * 256 + r1a[t][reg];
                const float yr = fmaf((float)ri, rmul_[reg], roff_[reg]);
                vr2 = vr2 + (yr - vr2) * 0.5f;
                if (vr2 - 1.0f >= 0.0f) { val += 1u; vr2 = 0.0f; }
                pack[t] |= val << (reg * 8);
            }
        }

        // in-wave 4x4 byte transpose across r3 lanes: co-major -> pixel-major
#pragma unroll
        for (int t = 0; t < 4; ++t) {
            unsigned u = pack[t];
            unsigned pt = __shfl_xor(u, 1);
            u = (r3 & 1) ? ((u & 0xFF00FF00u) | ((pt >> 8) & 0x00FF00FFu))
                         : ((u & 0x00FF00FFu) | ((pt << 8) & 0xFF00FF00u));
            pt = __shfl_xor(u, 2);
            u = (r3 & 2) ? ((u & 0xFFFF0000u) | (pt >> 16))
                         : ((u & 0x0000FFFFu) | (pt << 16));
            pack[t] = u;
        }

        __syncthreads();   // bar1: ring + stg reads of this/prev pass done

        if (p < 3) {       // commit prefetched rows into retired slots
            char* dA = &lds[LDS_RING + ((h0 + 4) & 3) * RING_ROW];
            char* dB = &lds[LDS_RING + ((h0 + 5) & 3) * RING_ROW];
            *(uint4*)(dA + tid * 16) = pfa0;
            *(uint4*)(dB + tid * 16) = pfb0;
            if (tid < 16) {
                *(uint4*)(dA + (tid + 512) * 16) = pfa1;
                *(uint4*)(dB + (tid + 512) * 16) = pfb1;
            }
        }
#pragma unroll
        for (int t = 0; t < 4; ++t)
            *(unsigned*)&lds[stg0 + t * 1024] = pack[t];
        __syncthreads();   // bar2: staged bytes + new ring rows visible

        // full-line stores: 16 consecutive lanes cover one 256-B row chunk
#pragma unroll
        for (int it = 0; it < 4; ++it) {
            const int u = it * 512 + tid;        // dword index 0..2047
            const int q4  = u & 15;
            const int cs  = (u >> 4) & 15;
            const int tt  = (u >> 8) & 3;
            const int rg2 = u >> 10;
            const unsigned dv = *(const unsigned*)
                &lds[LDS_STG + (((rg2 * 4 + tt) * 16 + cs) * 16 + (q4 ^ ((cs & 7) << 1))) * 4];
            f32x4 f;
            f[0] = (float)(dv & 0xffu);
            f[1] = (float)((dv >> 8) & 0xffu);
            f[2] = (float)((dv >> 16) & 0xffu);
            f[3] = (float)((dv >> 24) & 0xffu);
            float* op = out + (((size_t)(tt * 8 + b) * 256 + coblk * 16 + cs) << 14)
                            + (h0 + rg2) * 128 + wbase + q4 * 4;
            *(f32x4*)op = f;
        }
    }
}

extern "C" void kernel_launch(void* const* d_in, const int* in_sizes, int n_in,
                              void* d_out, int out_size, void* d_ws, size_t ws_size,
                              hipStream_t stream) {
    const float* x  = (const float*)d_in[0];
    const float* w0 = (const float*)d_in[1];
    const float* g0 = (const float*)d_in[2];
    const float* b0 = (const float*)d_in[3];
    const float* m0 = (const float*)d_in[4];
    const float* v0 = (const float*)d_in[5];
    const float* w1 = (const float*)d_in[6];
    const float* g1 = (const float*)d_in[7];
    const float* b1 = (const float*)d_in[8];
    const float* m1 = (const float*)d_in[9];
    const float* v1 = (const float*)d_in[10];
    const float* wr = (const float*)d_in[11];
    const float* gr = (const float*)d_in[12];
    const float* br = (const float*)d_in[13];
    const float* mr = (const float*)d_in[14];
    const float* vr = (const float*)d_in[15];

    unsigned char* ws = (unsigned char*)d_ws;
    const int n16 = (int)(SP_SIZE / 16);

    zero_ws_kernel<<<dim3(2048), dim3(256), 0, stream>>>((uint4*)ws, n16);
    prep_kernel<<<dim3(512), dim3(256), 0, stream>>>(w1, wr, g1, v1, b1, m1, gr, vr, br, mr, ws);
    stem_kernel<<<dim3(2, 128, 8), dim3(256), 0, stream>>>(x, w0, g0, b0, m0, v0, ws);
    main_i8_2r<<<dim3(4096), dim3(512), 0, stream>>>(ws, (float*)d_out);
}

// Round 10
// 451.957 us; speedup vs baseline: 1.9860x; 1.0530x over previous
//
#include <hip/hip_runtime.h>
#include <math.h>

#define T_  4
#define B_  8
#define C1  128
#define C2  256
#define H_  128
#define W_  128
#define BN_EPS 1e-5f

// ---- workspace layout (identical to rounds 4-9) ----
// sp: packed spikes uint8 [B][131 rows][130 pix][128 ci], bits0-3 = t0..t3,
//     byte offset within pixel block swizzled: c ^ ((pix&7)<<4)
#define SP_BSTR  2179840ull              // 131*130*128
#define SP_SIZE  17438720ull             // 8 * SP_BSTR
#define AZ0_OFF  SP_SIZE                 // 16coblk*9tap*2cq*1024 i8 digit0
#define AZ_SIZE  294912ull
#define AZ1_OFF  (AZ0_OFF + AZ_SIZE)
#define AR0_OFF  (AZ1_OFF + AZ_SIZE)     // 16coblk*2cq*1024
#define AR_SIZE  32768ull
#define AR1_OFF  (AR0_OFF + AR_SIZE)
#define PRM_OFF  (AR1_OFF + AR_SIZE)     // 1024 f32: zmul|zoff|rmul|roff

// ---- main-kernel LDS (60416 B -> 2 blocks/CU = 16 waves/CU) ----
#define RING_ROW 8448                    // 66 pix * 128 B
#define LDS_AZ1  0                       // 18432
#define LDS_RING 18432                   // 4 * 8448 = 33792
#define LDS_STG  52224                   // 2rg * 4t * 16co * 16dw * 4B = 8192
#define LDS_TOT  60416

typedef __attribute__((ext_vector_type(4))) int i32x4;
typedef __attribute__((ext_vector_type(4))) float f32x4;

#define MFI8(acc, A, Bv) acc = __builtin_amdgcn_mfma_i32_16x16x64_i8(A, Bv, acc, 0, 0, 0)

// Zero only the halo of sp (rows 0 & 129 full; pixels 0 & 129 of rows 1..128).
// Interior is fully overwritten by stem_kernel. 516 pixel-blocks per b.
__global__ __launch_bounds__(256) void zero_halo_kernel(unsigned char* __restrict__ sp) {
    const int i = blockIdx.x * 256 + threadIdx.x;   // 0..33023
    const int v  = i & 7;                            // uint4 within 128-B block
    const int pbg = i >> 3;                          // 0..4127
    const int b  = pbg / 516;
    const int pb = pbg - b * 516;
    int row, pix;
    if (pb < 260) { row = (pb < 130) ? 0 : 129; pix = (pb < 130) ? pb : pb - 130; }
    else { const int e = pb - 260; row = 1 + (e >> 1); pix = (e & 1) ? 129 : 0; }
    uint4* dst = (uint4*)(sp + (size_t)b * SP_BSTR + ((size_t)row * 130 + pix) * 128);
    dst[v] = make_uint4(0u, 0u, 0u, 0u);
}

// Quantize weights to per-co 15-bit fixed point, split into 2 signed i8 digits,
// packed in MFMA A-fragment order (k = cq*64 + q*16 + j). Blocks 0-255: z (w1),
// blocks 256-511: r (wr). Also writes folded BN params.
__global__ __launch_bounds__(256) void prep_kernel(
    const float* __restrict__ w1, const float* __restrict__ wr,
    const float* __restrict__ g1, const float* __restrict__ v1,
    const float* __restrict__ b1, const float* __restrict__ m1,
    const float* __restrict__ gr, const float* __restrict__ vr,
    const float* __restrict__ br, const float* __restrict__ mr,
    unsigned char* __restrict__ ws)
{
    __shared__ float red[256];
    const int tid = threadIdx.x;
    const bool is_r = blockIdx.x >= 256;
    const int co = blockIdx.x & 255;
    const int n = is_r ? 128 : 1152;
    const float* wsrc = is_r ? (wr + co * 128) : (w1 + co * 1152);

    float mx = 0.0f;
    for (int i = tid; i < n; i += 256) mx = fmaxf(mx, fabsf(wsrc[i]));
    red[tid] = mx;
    __syncthreads();
    for (int s = 128; s > 0; s >>= 1) {
        if (tid < s) red[tid] = fmaxf(red[tid], red[tid + s]);
        __syncthreads();
    }
    const float scale = red[0];
    const float qs = 32638.0f / scale;

    char* d0p = (char*)(ws + (is_r ? AR0_OFF : AZ0_OFF));
    char* d1p = (char*)(ws + (is_r ? AR1_OFF : AZ1_OFF));
    for (int i = tid; i < n; i += 256) {
        const int wq = __float2int_rn(wsrc[i] * qs);
        const int d1 = ((wq + 128) & 255) - 128;
        const int d0 = (wq - d1) >> 8;
        int ci, tap;
        if (is_r) { ci = i; tap = 0; } else { ci = i / 9; tap = i - ci * 9; }
        const int cq = ci >> 6, qq = (ci >> 4) & 3, jj = ci & 15;
        const int addr = is_r
            ? ((co >> 4) * 2048 + cq * 1024 + qq * 256 + (co & 15) * 16 + jj)
            : ((co >> 4) * 18432 + (tap * 2 + cq) * 1024 + qq * 256 + (co & 15) * 16 + jj);
        d0p[addr] = (char)d0;
        d1p[addr] = (char)d1;
    }
    if (tid == 0) {
        float* prm = (float*)(ws + PRM_OFF);
        if (!is_r) {
            const float s1 = g1[co] * (1.0f / sqrtf(v1[co] + BN_EPS));
            prm[co] = (scale / 32638.0f) * s1;
            prm[256 + co] = b1[co] - m1[co] * s1;
        } else {
            const float s2 = gr[co] * (1.0f / sqrtf(vr[co] + BN_EPS));
            prm[512 + co] = (scale / 32638.0f) * s2;
            prm[768 + co] = br[co] - mr[co] * s2;
        }
    }
}

// Stem: conv3x3 (2->128) + BN + LIF, writes packed (byte-swizzled) spikes.
__global__ __launch_bounds__(256) void stem_kernel(
    const float* __restrict__ x, const float* __restrict__ w0,
    const float* __restrict__ g0, const float* __restrict__ b0,
    const float* __restrict__ m0, const float* __restrict__ v0,
    unsigned char* __restrict__ sp)
{
    const int wseg = blockIdx.x;
    const int h    = blockIdx.y;
    const int b    = blockIdx.z;
    const int lane = threadIdx.x & 63;
    const int cg   = threadIdx.x >> 6;
    const int w    = wseg * 64 + lane;

    __shared__ float wl[2304];
    __shared__ float sc0s[128], m0s[128], b0s[128];

    for (int i = threadIdx.x; i < 2304; i += 256) wl[i] = w0[i];
    if (threadIdx.x < 128) {
        const int c = threadIdx.x;
        sc0s[c] = g0[c] * (1.0f / sqrtf(v0[c] + BN_EPS));
        m0s[c] = m0[c]; b0s[c] = b0[c];
    }
    __syncthreads();

    float xv[4][2][3][3];
#pragma unroll
    for (int t = 0; t < 4; ++t)
#pragma unroll
        for (int ci = 0; ci < 2; ++ci)
#pragma unroll
            for (int dh = 0; dh < 3; ++dh)
#pragma unroll
                for (int dw = 0; dw < 3; ++dw) {
                    const int hh = h + dh - 1, ww = w + dw - 1;
                    const bool ok = ((unsigned)hh < 128u) && ((unsigned)ww < 128u);
                    xv[t][ci][dh][dw] = ok ? x[(((size_t)(t * 8 + b) * 2 + ci) * 128 + hh) * 128 + ww] : 0.0f;
                }

    const int pix = w + 1;
    const int sw = (pix & 7) << 4;
    unsigned char* dst = sp + ((size_t)b * SP_BSTR) + ((size_t)((h + 1) * 130 + pix)) * 128;
    for (int i = 0; i < 8; ++i) {
        unsigned dwv = 0u;
#pragma unroll
        for (int j = 0; j < 4; ++j) {
            const int c = cg * 32 + i * 4 + j;
            float wreg[18];
#pragma unroll
            for (int k = 0; k < 18; ++k) wreg[k] = wl[c * 18 + k];
            const float sc = sc0s[c], mm = m0s[c], bb = b0s[c];
            float v = 0.0f; unsigned bits = 0u;
#pragma unroll
            for (int t = 0; t < 4; ++t) {
                float sum = 0.0f;
#pragma unroll
                for (int ci = 0; ci < 2; ++ci)
#pragma unroll
                    for (int dh = 0; dh < 3; ++dh)
#pragma unroll
                        for (int dw = 0; dw < 3; ++dw)
                            sum += xv[t][ci][dh][dw] * wreg[ci * 9 + dh * 3 + dw];
                const float y = (sum - mm) * sc + bb;
                v = v + (y - v) * 0.5f;
                if (v - 1.0f >= 0.0f) { bits |= 1u << t; v = 0.0f; }
            }
            dwv |= bits << (j * 8);
        }
        *(unsigned*)(dst + ((cg * 32 + i * 4) ^ sw)) = dwv;
    }
}

// Main fused: conv3x3(z) + conv1x1(r) via mfma_i32_16x16x64_i8 (2 digits),
// BN + LIF in-lane, out = z_spike + r_spike via full-line staged stores.
// Block = 8 waves (512 thr): waves 0-3 -> row h0, waves 4-7 -> row h0+1.
// Single-AND decode: B bytes in {0, 2^t}; exact 2^-t via integer shift in
// the epilogue (z0/z1 are multiples of 2^t) -> bit-identical numerics.
// LDS 60.4 KB -> 2 blocks/CU = 16 waves/CU. Grid 4096, XCD-swizzled.
__global__ __launch_bounds__(512, 2) void main_i8_2r(
    const unsigned char* __restrict__ ws, float* __restrict__ out)
{
    __shared__ __align__(16) char lds[LDS_TOT];

    const int bid = blockIdx.x;
    const int xcd = bid & 7;
    const int k   = bid >> 3;            // 0..511
    const int sub = k & 31;              // 0..31
    const int six = k >> 5;              // 0..15
    const int strip = six * 8 + xcd;     // 0..127
    const int coblk = sub >> 1;
    const int wseg  = sub & 1;
    const int hstrip = strip >> 3;
    const int b      = strip & 7;

    const int tid  = threadIdx.x;
    const int lane = tid & 63;
    const int wid  = tid >> 6;           // 0..7
    const int rg   = wid >> 2;           // row group 0/1
    const int ws4  = wid & 3;            // pixel sub-tile 0..3
    const int q    = lane >> 4;
    const int r16  = lane & 15;
    const int r3   = r16 & 3;
    const int ra   = r16 >> 2;
    const int wbase  = wseg * 64;
    const int hfirst = hstrip * 8;

    const unsigned char* spg = ws + (size_t)b * SP_BSTR + (size_t)wbase * 128;

    // ---- weights: Az digit0 + Ar (both digits) into registers, once ----
    i32x4 a0z[2][9];
#pragma unroll
    for (int cq = 0; cq < 2; ++cq)
#pragma unroll
        for (int tap = 0; tap < 9; ++tap)
            a0z[cq][tap] = *(const i32x4*)(ws + AZ0_OFF + coblk * 18432
                                           + ((tap * 2 + cq) << 10) + lane * 16);
    i32x4 ar0[2], ar1[2];
#pragma unroll
    for (int cq = 0; cq < 2; ++cq) {
        ar0[cq] = *(const i32x4*)(ws + AR0_OFF + coblk * 2048 + (cq << 10) + lane * 16);
        ar1[cq] = *(const i32x4*)(ws + AR1_OFF + coblk * 2048 + (cq << 10) + lane * 16);
    }

    // folded epilogue params per acc register (co = coblk*16 + q*4 + reg)
    const float* prm = (const float*)(ws + PRM_OFF);
    float zmul_[4], zoff_[4], rmul_[4], roff_[4];
#pragma unroll
    for (int reg = 0; reg < 4; ++reg) {
        const int co = coblk * 16 + q * 4 + reg;
        zmul_[reg] = prm[co];       zoff_[reg] = prm[256 + co];
        rmul_[reg] = prm[512 + co]; roff_[reg] = prm[768 + co];
    }

    // ---- stage Az digit1 (18 KB) + ring rows hfirst..hfirst+3 (66-pix) ----
    {
        const uint4* s = (const uint4*)(ws + AZ1_OFF + (size_t)coblk * 18432);
        uint4* d = (uint4*)&lds[LDS_AZ1];
        for (int i = tid; i < 1152; i += 512) d[i] = s[i];
    }
    for (int i = tid; i < 2112; i += 512) {      // 4 rows * 528 uint4
        const int rr = i / 528;
        const int off = (i - rr * 528) * 16;
        const int gr = hfirst + rr;
        *(uint4*)&lds[LDS_RING + (gr & 3) * RING_ROW + off] =
            *(const uint4*)(spg + (size_t)gr * 16640 + off);
    }
    __syncthreads();

    const int plbase = ws4 * 16 + r16;           // local output pixel (0..63)
    const int co16 = q * 4 + r3;
    const int pq   = ws4 * 4 + ra;
    const int swz  = (co16 & 7) << 1;
    const int stg0 = LDS_STG + ((rg * 4 * 16 + co16) * 16 + (pq ^ swz)) * 4;

    for (int p = 0; p < 4; ++p) {
        const int h0 = hfirst + 2 * p;
        const int my_row = h0 + rg;

        // prefetch next 2 sp rows (gr = h0+4, h0+5) into registers
        uint4 pfa0, pfa1, pfb0, pfb1;
        if (p < 3) {
            const unsigned char* s0 = spg + (size_t)(h0 + 4) * 16640;
            const unsigned char* s1 = spg + (size_t)(h0 + 5) * 16640;
            pfa0 = *(const uint4*)(s0 + tid * 16);
            pfb0 = *(const uint4*)(s1 + tid * 16);
            if (tid < 16) {
                pfa1 = *(const uint4*)(s0 + (tid + 512) * 16);
                pfb1 = *(const uint4*)(s1 + (tid + 512) * 16);
            }
        }

        i32x4 z0[4], z1[4], r0a[4], r1a[4];
#pragma unroll
        for (int t = 0; t < 4; ++t) {
            z0[t] = (i32x4)(0); z1[t] = (i32x4)(0);
            r0a[t] = (i32x4)(0); r1a[t] = (i32x4)(0);
        }

#pragma unroll
        for (int cq = 0; cq < 2; ++cq) {
#pragma unroll
            for (int kw = 0; kw < 3; ++kw) {
                i32x4 a1[3];
#pragma unroll
                for (int kh = 0; kh < 3; ++kh)
                    a1[kh] = *(const i32x4*)&lds[LDS_AZ1 + (((kh * 3 + kw) * 2 + cq) << 10)
                                                 + lane * 16];
                const int pl = plbase + kw;
                const int addrb = pl * 128 + ((cq * 64 + q * 16) ^ ((pl & 7) << 4));
#pragma unroll
                for (int rr = 0; rr < 3; ++rr) {
                    const int slot = (my_row + rr) & 3;   // input sp row my_row+rr
                    const uint4 dd = *(const uint4*)&lds[LDS_RING + slot * RING_ROW + addrb];
#pragma unroll
                    for (int t = 0; t < 4; ++t) {
                        const unsigned Mt = 0x01010101u << t;   // single-AND decode
                        i32x4 bt;
                        bt[0] = (int)(dd.x & Mt);
                        bt[1] = (int)(dd.y & Mt);
                        bt[2] = (int)(dd.z & Mt);
                        bt[3] = (int)(dd.w & Mt);
                        MFI8(z0[t], a0z[cq][rr * 3 + kw], bt);
                        MFI8(z1[t], a1[rr], bt);
                        if (kw == 1 && rr == 1) {
                            MFI8(r0a[t], ar0[cq], bt);
                            MFI8(r1a[t], ar1[cq], bt);
                        }
                    }
                }
            }
        }

        // Epilogue: combine digits (accs are exact multiples of 2^t -> shift),
        // BN + LIF (in-lane t-series), byte-pack
        unsigned pack[4] = {0u, 0u, 0u, 0u};
#pragma unroll
        for (int reg = 0; reg < 4; ++reg) {
            float vz = 0.0f, vr2 = 0.0f;
#pragma unroll
            for (int t = 0; t < 4; ++t) {
                const int zi = (z0[t][reg] * 256 + z1[t][reg]) >> t;
                const float yz = fmaf((float)zi, zmul_[reg], zoff_[reg]);
                vz = vz + (yz - vz) * 0.5f;
                unsigned val = 0u;
                if (vz - 1.0f >= 0.0f) { val = 1u; vz = 0.0f; }
                const int ri = (r0a[t][reg] * 256 + r1a[t][reg]) >> t;
                const float yr = fmaf((float)ri, rmul_[reg], roff_[reg]);
                vr2 = vr2 + (yr - vr2) * 0.5f;
                if (vr2 - 1.0f >= 0.0f) { val += 1u; vr2 = 0.0f; }
                pack[t] |= val << (reg * 8);
            }
        }

        // in-wave 4x4 byte transpose across r3 lanes: co-major -> pixel-major
#pragma unroll
        for (int t = 0; t < 4; ++t) {
            unsigned u = pack[t];
            unsigned pt = __shfl_xor(u, 1);
            u = (r3 & 1) ? ((u & 0xFF00FF00u) | ((pt >> 8) & 0x00FF00FFu))
                         : ((u & 0x00FF00FFu) | ((pt << 8) & 0xFF00FF00u));
            pt = __shfl_xor(u, 2);
            u = (r3 & 2) ? ((u & 0xFFFF0000u) | (pt >> 16))
                         : ((u & 0x0000FFFFu) | (pt << 16));
            pack[t] = u;
        }

        __syncthreads();   // bar1: ring + stg reads of this/prev pass done

        if (p < 3) {       // commit prefetched rows into retired slots
            char* dA = &lds[LDS_RING + ((h0 + 4) & 3) * RING_ROW];
            char* dB = &lds[LDS_RING + ((h0 + 5) & 3) * RING_ROW];
            *(uint4*)(dA + tid * 16) = pfa0;
            *(uint4*)(dB + tid * 16) = pfb0;
            if (tid < 16) {
                *(uint4*)(dA + (tid + 512) * 16) = pfa1;
                *(uint4*)(dB + (tid + 512) * 16) = pfb1;
            }
        }
#pragma unroll
        for (int t = 0; t < 4; ++t)
            *(unsigned*)&lds[stg0 + t * 1024] = pack[t];
        __syncthreads();   // bar2: staged bytes + new ring rows visible

        // full-line stores: 16 consecutive lanes cover one 256-B row chunk
#pragma unroll
        for (int it = 0; it < 4; ++it) {
            const int u = it * 512 + tid;        // dword index 0..2047
            const int q4  = u & 15;
            const int cs  = (u >> 4) & 15;
            const int tt  = (u >> 8) & 3;
            const int rg2 = u >> 10;
            const unsigned dv = *(const unsigned*)
                &lds[LDS_STG + (((rg2 * 4 + tt) * 16 + cs) * 16 + (q4 ^ ((cs & 7) << 1))) * 4];
            f32x4 f;
            f[0] = (float)(dv & 0xffu);
            f[1] = (float)((dv >> 8) & 0xffu);
            f[2] = (float)((dv >> 16) & 0xffu);
            f[3] = (float)((dv >> 24) & 0xffu);
            float* op = out + (((size_t)(tt * 8 + b) * 256 + coblk * 16 + cs) << 14)
                            + (h0 + rg2) * 128 + wbase + q4 * 4;
            *(f32x4*)op = f;
        }
    }
}

extern "C" void kernel_launch(void* const* d_in, const int* in_sizes, int n_in,
                              void* d_out, int out_size, void* d_ws, size_t ws_size,
                              hipStream_t stream) {
    const float* x  = (const float*)d_in[0];
    const float* w0 = (const float*)d_in[1];
    const float* g0 = (const float*)d_in[2];
    const float* b0 = (const float*)d_in[3];
    const float* m0 = (const float*)d_in[4];
    const float* v0 = (const float*)d_in[5];
    const float* w1 = (const float*)d_in[6];
    const float* g1 = (const float*)d_in[7];
    const float* b1 = (const float*)d_in[8];
    const float* m1 = (const float*)d_in[9];
    const float* v1 = (const float*)d_in[10];
    const float* wr = (const float*)d_in[11];
    const float* gr = (const float*)d_in[12];
    const float* br = (const float*)d_in[13];
    const float* mr = (const float*)d_in[14];
    const float* vr = (const float*)d_in[15];

    unsigned char* ws = (unsigned char*)d_ws;

    zero_halo_kernel<<<dim3(129), dim3(256), 0, stream>>>(ws);
    prep_kernel<<<dim3(512), dim3(256), 0, stream>>>(w1, wr, g1, v1, b1, m1, gr, vr, br, mr, ws);
    stem_kernel<<<dim3(2, 128, 8), dim3(256), 0, stream>>>(x, w0, g0, b0, m0, v0, ws);
    main_i8_2r<<<dim3(4096), dim3(512), 0, stream>>>(ws, (float*)d_out);
}

// Round 11
// 428.719 us; speedup vs baseline: 2.0937x; 1.0542x over previous
//
#include <hip/hip_runtime.h>
#include <math.h>

#define T_  4
#define B_  8
#define C1  128
#define C2  256
#define H_  128
#define W_  128
#define BN_EPS 1e-5f

// ---- workspace layout (identical to rounds 4-10) ----
// sp: packed spikes uint8 [B][131 rows][130 pix][128 ci], bits0-3 = t0..t3,
//     byte offset within pixel block swizzled: c ^ ((pix&7)<<4)
#define SP_BSTR  2179840ull              // 131*130*128
#define SP_SIZE  17438720ull             // 8 * SP_BSTR
#define AZ0_OFF  SP_SIZE                 // 16coblk*9tap*2cq*1024 i8 digit0
#define AZ_SIZE  294912ull
#define AZ1_OFF  (AZ0_OFF + AZ_SIZE)
#define AR0_OFF  (AZ1_OFF + AZ_SIZE)     // 16coblk*2cq*1024
#define AR_SIZE  32768ull
#define AR1_OFF  (AR0_OFF + AR_SIZE)
#define PRM_OFF  (AR1_OFF + AR_SIZE)     // 1024 f32 (HALVED): zmulh|zoffh|rmulh|roffh

// ---- main-kernel LDS (60416 B -> 2 blocks/CU = 16 waves/CU) ----
#define RING_ROW 8448                    // 66 pix * 128 B
#define LDS_AZ1  0                       // 18432
#define LDS_RING 18432                   // 4 * 8448 = 33792
#define LDS_STG  52224                   // 2rg * 4t * 16co * 16dw * 4B = 8192
#define LDS_TOT  60416

typedef __attribute__((ext_vector_type(4))) int i32x4;
typedef __attribute__((ext_vector_type(4))) float f32x4;

#define MFI8(acc, A, Bv) acc = __builtin_amdgcn_mfma_i32_16x16x64_i8(A, Bv, acc, 0, 0, 0)

// Zero only the halo of sp (rows 0 & 129 full; pixels 0 & 129 of rows 1..128).
__global__ __launch_bounds__(256) void zero_halo_kernel(unsigned char* __restrict__ sp) {
    const int i = blockIdx.x * 256 + threadIdx.x;   // 0..33023
    const int v  = i & 7;
    const int pbg = i >> 3;                          // 0..4127
    const int b  = pbg / 516;
    const int pb = pbg - b * 516;
    int row, pix;
    if (pb < 260) { row = (pb < 130) ? 0 : 129; pix = (pb < 130) ? pb : pb - 130; }
    else { const int e = pb - 260; row = 1 + (e >> 1); pix = (e & 1) ? 129 : 0; }
    uint4* dst = (uint4*)(sp + (size_t)b * SP_BSTR + ((size_t)row * 130 + pix) * 128);
    dst[v] = make_uint4(0u, 0u, 0u, 0u);
}

// Quantize weights to per-co 15-bit fixed point, split into 2 signed i8 digits,
// packed in MFMA A-fragment order. Blocks 0-255: z (w1), 256-511: r (wr).
// BN params are folded AND pre-halved (epilogue uses v' = fma(v,0.5,yh)).
__global__ __launch_bounds__(256) void prep_kernel(
    const float* __restrict__ w1, const float* __restrict__ wr,
    const float* __restrict__ g1, const float* __restrict__ v1,
    const float* __restrict__ b1, const float* __restrict__ m1,
    const float* __restrict__ gr, const float* __restrict__ vr,
    const float* __restrict__ br, const float* __restrict__ mr,
    unsigned char* __restrict__ ws)
{
    __shared__ float red[256];
    const int tid = threadIdx.x;
    const bool is_r = blockIdx.x >= 256;
    const int co = blockIdx.x & 255;
    const int n = is_r ? 128 : 1152;
    const float* wsrc = is_r ? (wr + co * 128) : (w1 + co * 1152);

    float mx = 0.0f;
    for (int i = tid; i < n; i += 256) mx = fmaxf(mx, fabsf(wsrc[i]));
    red[tid] = mx;
    __syncthreads();
    for (int s = 128; s > 0; s >>= 1) {
        if (tid < s) red[tid] = fmaxf(red[tid], red[tid + s]);
        __syncthreads();
    }
    const float scale = red[0];
    const float qs = 32638.0f / scale;

    char* d0p = (char*)(ws + (is_r ? AR0_OFF : AZ0_OFF));
    char* d1p = (char*)(ws + (is_r ? AR1_OFF : AZ1_OFF));
    for (int i = tid; i < n; i += 256) {
        const int wq = __float2int_rn(wsrc[i] * qs);
        const int d1 = ((wq + 128) & 255) - 128;
        const int d0 = (wq - d1) >> 8;
        int ci, tap;
        if (is_r) { ci = i; tap = 0; } else { ci = i / 9; tap = i - ci * 9; }
        const int cq = ci >> 6, qq = (ci >> 4) & 3, jj = ci & 15;
        const int addr = is_r
            ? ((co >> 4) * 2048 + cq * 1024 + qq * 256 + (co & 15) * 16 + jj)
            : ((co >> 4) * 18432 + (tap * 2 + cq) * 1024 + qq * 256 + (co & 15) * 16 + jj);
        d0p[addr] = (char)d0;
        d1p[addr] = (char)d1;
    }
    if (tid == 0) {
        float* prm = (float*)(ws + PRM_OFF);
        if (!is_r) {
            const float s1 = g1[co] * (1.0f / sqrtf(v1[co] + BN_EPS));
            prm[co]       = 0.5f * (scale / 32638.0f) * s1;
            prm[256 + co] = 0.5f * (b1[co] - m1[co] * s1);
        } else {
            const float s2 = gr[co] * (1.0f / sqrtf(vr[co] + BN_EPS));
            prm[512 + co] = 0.5f * (scale / 32638.0f) * s2;
            prm[768 + co] = 0.5f * (br[co] - mr[co] * s2);
        }
    }
}

// Stem: conv3x3 (2->128) + BN + LIF, writes packed (byte-swizzled) spikes.
// Weight tile padded to 20 floats/channel so per-channel reads vectorize.
__global__ __launch_bounds__(256) void stem_kernel(
    const float* __restrict__ x, const float* __restrict__ w0,
    const float* __restrict__ g0, const float* __restrict__ b0,
    const float* __restrict__ m0, const float* __restrict__ v0,
    unsigned char* __restrict__ sp)
{
    const int wseg = blockIdx.x;
    const int h    = blockIdx.y;
    const int b    = blockIdx.z;
    const int lane = threadIdx.x & 63;
    const int cg   = threadIdx.x >> 6;
    const int w    = wseg * 64 + lane;

    __shared__ __align__(16) float wl[2560];     // [c][20] (18 used)
    __shared__ float sc0s[128], m0s[128], b0s[128];

    for (int i = threadIdx.x; i < 2304; i += 256) {
        const int c = i / 18, k2 = i - c * 18;
        wl[c * 20 + k2] = w0[i];
    }
    if (threadIdx.x < 128) {
        const int c = threadIdx.x;
        sc0s[c] = g0[c] * (1.0f / sqrtf(v0[c] + BN_EPS));
        m0s[c] = m0[c]; b0s[c] = b0[c];
    }
    __syncthreads();

    float xv[4][2][3][3];
#pragma unroll
    for (int t = 0; t < 4; ++t)
#pragma unroll
        for (int ci = 0; ci < 2; ++ci)
#pragma unroll
            for (int dh = 0; dh < 3; ++dh)
#pragma unroll
                for (int dw = 0; dw < 3; ++dw) {
                    const int hh = h + dh - 1, ww = w + dw - 1;
                    const bool ok = ((unsigned)hh < 128u) && ((unsigned)ww < 128u);
                    xv[t][ci][dh][dw] = ok ? x[(((size_t)(t * 8 + b) * 2 + ci) * 128 + hh) * 128 + ww] : 0.0f;
                }

    const int pix = w + 1;
    const int sw = (pix & 7) << 4;
    unsigned char* dst = sp + ((size_t)b * SP_BSTR) + ((size_t)((h + 1) * 130 + pix)) * 128;
    for (int i = 0; i < 8; ++i) {
        unsigned dwv = 0u;
#pragma unroll
        for (int j = 0; j < 4; ++j) {
            const int c = cg * 32 + i * 4 + j;
            float wreg[18];
            {
                const float4 wa = *(const float4*)&wl[c * 20];
                const float4 wb = *(const float4*)&wl[c * 20 + 4];
                const float4 wc = *(const float4*)&wl[c * 20 + 8];
                const float4 wd = *(const float4*)&wl[c * 20 + 12];
                const float2 we = *(const float2*)&wl[c * 20 + 16];
                wreg[0]=wa.x; wreg[1]=wa.y; wreg[2]=wa.z; wreg[3]=wa.w;
                wreg[4]=wb.x; wreg[5]=wb.y; wreg[6]=wb.z; wreg[7]=wb.w;
                wreg[8]=wc.x; wreg[9]=wc.y; wreg[10]=wc.z; wreg[11]=wc.w;
                wreg[12]=wd.x; wreg[13]=wd.y; wreg[14]=wd.z; wreg[15]=wd.w;
                wreg[16]=we.x; wreg[17]=we.y;
            }
            const float sc = sc0s[c], mm = m0s[c], bb = b0s[c];
            float v = 0.0f; unsigned bits = 0u;
#pragma unroll
            for (int t = 0; t < 4; ++t) {
                float sum = 0.0f;
#pragma unroll
                for (int ci = 0; ci < 2; ++ci)
#pragma unroll
                    for (int dh = 0; dh < 3; ++dh)
#pragma unroll
                        for (int dw = 0; dw < 3; ++dw)
                            sum += xv[t][ci][dh][dw] * wreg[ci * 9 + dh * 3 + dw];
                const float y = (sum - mm) * sc + bb;
                v = v + (y - v) * 0.5f;
                if (v - 1.0f >= 0.0f) { bits |= 1u << t; v = 0.0f; }
            }
            dwv |= bits << (j * 8);
        }
        *(unsigned*)(dst + ((cg * 32 + i * 4) ^ sw)) = dwv;
    }
}

// Main fused: conv3x3(z) + conv1x1(r) via mfma_i32_16x16x64_i8 (2 digits),
// BN + LIF in-lane (halved-constant fma form), full-line staged stores.
// Block = 8 waves: waves 0-3 -> row h0, waves 4-7 -> row h0+1; 4 passes.
// s_setprio(1) wraps the decode+MFMA region (2 independent blocks/CU give
// the scheduler phase diversity to arbitrate).
__global__ __launch_bounds__(512, 2) void main_i8_2r(
    const unsigned char* __restrict__ ws, float* __restrict__ out)
{
    __shared__ __align__(16) char lds[LDS_TOT];

    const int bid = blockIdx.x;
    const int xcd = bid & 7;
    const int k   = bid >> 3;
    const int sub = k & 31;
    const int six = k >> 5;
    const int strip = six * 8 + xcd;
    const int coblk = sub >> 1;
    const int wseg  = sub & 1;
    const int hstrip = strip >> 3;
    const int b      = strip & 7;

    const int tid  = threadIdx.x;
    const int lane = tid & 63;
    const int wid  = tid >> 6;
    const int rg   = wid >> 2;
    const int ws4  = wid & 3;
    const int q    = lane >> 4;
    const int r16  = lane & 15;
    const int r3   = r16 & 3;
    const int ra   = r16 >> 2;
    const int wbase  = wseg * 64;
    const int hfirst = hstrip * 8;

    const unsigned char* spg = ws + (size_t)b * SP_BSTR + (size_t)wbase * 128;

    // ---- weights: Az digit0 + Ar (both digits) into registers, once ----
    i32x4 a0z[2][9];
#pragma unroll
    for (int cq = 0; cq < 2; ++cq)
#pragma unroll
        for (int tap = 0; tap < 9; ++tap)
            a0z[cq][tap] = *(const i32x4*)(ws + AZ0_OFF + coblk * 18432
                                           + ((tap * 2 + cq) << 10) + lane * 16);
    i32x4 ar0[2], ar1[2];
#pragma unroll
    for (int cq = 0; cq < 2; ++cq) {
        ar0[cq] = *(const i32x4*)(ws + AR0_OFF + coblk * 2048 + (cq << 10) + lane * 16);
        ar1[cq] = *(const i32x4*)(ws + AR1_OFF + coblk * 2048 + (cq << 10) + lane * 16);
    }

    // folded+halved epilogue params per acc register
    const float* prm = (const float*)(ws + PRM_OFF);
    float zmul_[4], zoff_[4], rmul_[4], roff_[4];
#pragma unroll
    for (int reg = 0; reg < 4; ++reg) {
        const int co = coblk * 16 + q * 4 + reg;
        zmul_[reg] = prm[co];       zoff_[reg] = prm[256 + co];
        rmul_[reg] = prm[512 + co]; roff_[reg] = prm[768 + co];
    }

    // ---- stage Az digit1 (18 KB) + ring rows hfirst..hfirst+3 (66-pix) ----
    {
        const uint4* s = (const uint4*)(ws + AZ1_OFF + (size_t)coblk * 18432);
        uint4* d = (uint4*)&lds[LDS_AZ1];
        for (int i = tid; i < 1152; i += 512) d[i] = s[i];
    }
    for (int i = tid; i < 2112; i += 512) {
        const int rr = i / 528;
        const int off = (i - rr * 528) * 16;
        const int gr = hfirst + rr;
        *(uint4*)&lds[LDS_RING + (gr & 3) * RING_ROW + off] =
            *(const uint4*)(spg + (size_t)gr * 16640 + off);
    }
    __syncthreads();

    const int plbase = ws4 * 16 + r16;
    const int co16 = q * 4 + r3;
    const int pq   = ws4 * 4 + ra;
    const int swz  = (co16 & 7) << 1;
    const int stg0 = LDS_STG + ((rg * 4 * 16 + co16) * 16 + (pq ^ swz)) * 4;

    for (int p = 0; p < 4; ++p) {
        const int h0 = hfirst + 2 * p;
        const int my_row = h0 + rg;

        // prefetch next 2 sp rows (gr = h0+4, h0+5) into registers
        uint4 pfa0, pfa1, pfb0, pfb1;
        if (p < 3) {
            const unsigned char* s0 = spg + (size_t)(h0 + 4) * 16640;
            const unsigned char* s1 = spg + (size_t)(h0 + 5) * 16640;
            pfa0 = *(const uint4*)(s0 + tid * 16);
            pfb0 = *(const uint4*)(s1 + tid * 16);
            if (tid < 16) {
                pfa1 = *(const uint4*)(s0 + (tid + 512) * 16);
                pfb1 = *(const uint4*)(s1 + (tid + 512) * 16);
            }
        }

        i32x4 z0[4], z1[4], r0a[4], r1a[4];
#pragma unroll
        for (int t = 0; t < 4; ++t) {
            z0[t] = (i32x4)(0); z1[t] = (i32x4)(0);
            r0a[t] = (i32x4)(0); r1a[t] = (i32x4)(0);
        }

        __builtin_amdgcn_s_setprio(1);
#pragma unroll
        for (int cq = 0; cq < 2; ++cq) {
#pragma unroll
            for (int kw = 0; kw < 3; ++kw) {
                i32x4 a1[3];
#pragma unroll
                for (int kh = 0; kh < 3; ++kh)
                    a1[kh] = *(const i32x4*)&lds[LDS_AZ1 + (((kh * 3 + kw) * 2 + cq) << 10)
                                                 + lane * 16];
                const int pl = plbase + kw;
                const int addrb = pl * 128 + ((cq * 64 + q * 16) ^ ((pl & 7) << 4));
#pragma unroll
                for (int rr = 0; rr < 3; ++rr) {
                    const int slot = (my_row + rr) & 3;
                    const uint4 dd = *(const uint4*)&lds[LDS_RING + slot * RING_ROW + addrb];
#pragma unroll
                    for (int t = 0; t < 4; ++t) {
                        const unsigned Mt = 0x01010101u << t;   // single-AND decode
                        i32x4 bt;
                        bt[0] = (int)(dd.x & Mt);
                        bt[1] = (int)(dd.y & Mt);
                        bt[2] = (int)(dd.z & Mt);
                        bt[3] = (int)(dd.w & Mt);
                        MFI8(z0[t], a0z[cq][rr * 3 + kw], bt);
                        MFI8(z1[t], a1[rr], bt);
                        if (kw == 1 && rr == 1) {
                            MFI8(r0a[t], ar0[cq], bt);
                            MFI8(r1a[t], ar1[cq], bt);
                        }
                    }
                }
            }
        }
        __builtin_amdgcn_s_setprio(0);

        // Epilogue: combine digits (exact 2^-t shift), BN + LIF (halved-const
        // fma form: v' = fma(v, 0.5, 0.5*y)), byte-pack
        unsigned pack[4] = {0u, 0u, 0u, 0u};
#pragma unroll
        for (int reg = 0; reg < 4; ++reg) {
            float vz = 0.0f, vr2 = 0.0f;
#pragma unroll
            for (int t = 0; t < 4; ++t) {
                const int zi = (z0[t][reg] * 256 + z1[t][reg]) >> t;
                const float yzh = fmaf((float)zi, zmul_[reg], zoff_[reg]);
                vz = fmaf(vz, 0.5f, yzh);
                unsigned val = 0u;
                if (vz >= 1.0f) { val = 1u; vz = 0.0f; }
                const int ri = (r0a[t][reg] * 256 + r1a[t][reg]) >> t;
                const float yrh = fmaf((float)ri, rmul_[reg], roff_[reg]);
                vr2 = fmaf(vr2, 0.5f, yrh);
                if (vr2 >= 1.0f) { val += 1u; vr2 = 0.0f; }
                pack[t] |= val << (reg * 8);
            }
        }

        // in-wave 4x4 byte transpose across r3 lanes: co-major -> pixel-major
#pragma unroll
        for (int t = 0; t < 4; ++t) {
            unsigned u = pack[t];
            unsigned pt = __shfl_xor(u, 1);
            u = (r3 & 1) ? ((u & 0xFF00FF00u) | ((pt >> 8) & 0x00FF00FFu))
                         : ((u & 0x00FF00FFu) | ((pt << 8) & 0xFF00FF00u));
            pt = __shfl_xor(u, 2);
            u = (r3 & 2) ? ((u & 0xFFFF0000u) | (pt >> 16))
                         : ((u & 0x0000FFFFu) | (pt << 16));
            pack[t] = u;
        }

        __syncthreads();   // bar1: ring + stg reads done

        if (p < 3) {       // commit prefetched rows into retired slots
            char* dA = &lds[LDS_RING + ((h0 + 4) & 3) * RING_ROW];
            char* dB = &lds[LDS_RING + ((h0 + 5) & 3) * RING_ROW];
            *(uint4*)(dA + tid * 16) = pfa0;
            *(uint4*)(dB + tid * 16) = pfb0;
            if (tid < 16) {
                *(uint4*)(dA + (tid + 512) * 16) = pfa1;
                *(uint4*)(dB + (tid + 512) * 16) = pfb1;
            }
        }
#pragma unroll
        for (int t = 0; t < 4; ++t)
            *(unsigned*)&lds[stg0 + t * 1024] = pack[t];
        __syncthreads();   // bar2: staged bytes + new ring rows visible

        // full-line stores: 16 consecutive lanes cover one 256-B row chunk
#pragma unroll
        for (int it = 0; it < 4; ++it) {
            const int u = it * 512 + tid;
            const int q4  = u & 15;
            const int cs  = (u >> 4) & 15;
            const int tt  = (u >> 8) & 3;
            const int rg2 = u >> 10;
            const unsigned dv = *(const unsigned*)
                &lds[LDS_STG + (((rg2 * 4 + tt) * 16 + cs) * 16 + (q4 ^ ((cs & 7) << 1))) * 4];
            f32x4 f;
            f[0] = (float)(dv & 0xffu);
            f[1] = (float)((dv >> 8) & 0xffu);
            f[2] = (float)((dv >> 16) & 0xffu);
            f[3] = (float)((dv >> 24) & 0xffu);
            float* op = out + (((size_t)(tt * 8 + b) * 256 + coblk * 16 + cs) << 14)
                            + (h0 + rg2) * 128 + wbase + q4 * 4;
            *(f32x4*)op = f;
        }
    }
}

extern "C" void kernel_launch(void* const* d_in, const int* in_sizes, int n_in,
                              void* d_out, int out_size, void* d_ws, size_t ws_size,
                              hipStream_t stream) {
    const float* x  = (const float*)d_in[0];
    const float* w0 = (const float*)d_in[1];
    const float* g0 = (const float*)d_in[2];
    const float* b0 = (const float*)d_in[3];
    const float* m0 = (const float*)d_in[4];
    const float* v0 = (const float*)d_in[5];
    const float* w1 = (const float*)d_in[6];
    const float* g1 = (const float*)d_in[7];
    const float* b1 = (const float*)d_in[8];
    const float* m1 = (const float*)d_in[9];
    const float* v1 = (const float*)d_in[10];
    const float* wr = (const float*)d_in[11];
    const float* gr = (const float*)d_in[12];
    const float* br = (const float*)d_in[13];
    const float* mr = (const float*)d_in[14];
    const float* vr = (const float*)d_in[15];

    unsigned char* ws = (unsigned char*)d_ws;

    zero_halo_kernel<<<dim3(129), dim3(256), 0, stream>>>(ws);
    prep_kernel<<<dim3(512), dim3(256), 0, stream>>>(w1, wr, g1, v1, b1, m1, gr, vr, br, mr, ws);
    stem_kernel<<<dim3(2, 128, 8), dim3(256), 0, stream>>>(x, w0, g0, b0, m0, v0, ws);
    main_i8_2r<<<dim3(4096), dim3(512), 0, stream>>>(ws, (float*)d_out);
}

// Round 12
// 399.263 us; speedup vs baseline: 2.2481x; 1.0738x over previous
//
#include <hip/hip_runtime.h>
#include <math.h>

#define T_  4
#define B_  8
#define C1  128
#define C2  256
#define H_  128
#define W_  128
#define BN_EPS 1e-5f

// ---- workspace layout (identical to rounds 4-11) ----
// sp: packed spikes uint8 [B][131 rows][130 pix][128 ci], bits0-3 = t0..t3,
//     byte offset within pixel block swizzled: c ^ ((pix&7)<<4)
#define SP_BSTR  2179840ull              // 131*130*128
#define SP_SIZE  17438720ull             // 8 * SP_BSTR
#define AZ0_OFF  SP_SIZE                 // 16coblk*9tap*2cq*1024 i8 digit0
#define AZ_SIZE  294912ull
#define AZ1_OFF  (AZ0_OFF + AZ_SIZE)
#define AR0_OFF  (AZ1_OFF + AZ_SIZE)     // 16coblk*2cq*1024
#define AR_SIZE  32768ull
#define AR1_OFF  (AR0_OFF + AR_SIZE)
#define PRM_OFF  (AR1_OFF + AR_SIZE)     // 1024 f32 (HALVED): zmulh|zoffh|rmulh|roffh

// ---- main-kernel LDS (60416 B -> 2 blocks/CU = 16 waves/CU) ----
#define RING_ROW 8448                    // 66 pix * 128 B
#define LDS_AZ1  0                       // 18432
#define LDS_RING 18432                   // 4 * 8448 = 33792
#define LDS_STG  52224                   // 2rg * 4t * 16co * 16dw * 4B = 8192
#define LDS_TOT  60416

typedef __attribute__((ext_vector_type(4))) int i32x4;
typedef __attribute__((ext_vector_type(4))) float f32x4;
typedef __attribute__((ext_vector_type(2))) float f32x2;

#define MFI8(acc, A, Bv) acc = __builtin_amdgcn_mfma_i32_16x16x64_i8(A, Bv, acc, 0, 0, 0)

// Zero only the halo of sp (rows 0 & 129 full; pixels 0 & 129 of rows 1..128).
__global__ __launch_bounds__(256) void zero_halo_kernel(unsigned char* __restrict__ sp) {
    const int i = blockIdx.x * 256 + threadIdx.x;   // 0..33023
    const int v  = i & 7;
    const int pbg = i >> 3;                          // 0..4127
    const int b  = pbg / 516;
    const int pb = pbg - b * 516;
    int row, pix;
    if (pb < 260) { row = (pb < 130) ? 0 : 129; pix = (pb < 130) ? pb : pb - 130; }
    else { const int e = pb - 260; row = 1 + (e >> 1); pix = (e & 1) ? 129 : 0; }
    uint4* dst = (uint4*)(sp + (size_t)b * SP_BSTR + ((size_t)row * 130 + pix) * 128);
    dst[v] = make_uint4(0u, 0u, 0u, 0u);
}

// Quantize weights to per-co 15-bit fixed point, split into 2 signed i8 digits,
// packed in MFMA A-fragment order. Blocks 0-255: z (w1), 256-511: r (wr).
// BN params are folded AND pre-halved (epilogue uses v' = fma(v,0.5,yh)).
__global__ __launch_bounds__(256) void prep_kernel(
    const float* __restrict__ w1, const float* __restrict__ wr,
    const float* __restrict__ g1, const float* __restrict__ v1,
    const float* __restrict__ b1, const float* __restrict__ m1,
    const float* __restrict__ gr, const float* __restrict__ vr,
    const float* __restrict__ br, const float* __restrict__ mr,
    unsigned char* __restrict__ ws)
{
    __shared__ float red[256];
    const int tid = threadIdx.x;
    const bool is_r = blockIdx.x >= 256;
    const int co = blockIdx.x & 255;
    const int n = is_r ? 128 : 1152;
    const float* wsrc = is_r ? (wr + co * 128) : (w1 + co * 1152);

    float mx = 0.0f;
    for (int i = tid; i < n; i += 256) mx = fmaxf(mx, fabsf(wsrc[i]));
    red[tid] = mx;
    __syncthreads();
    for (int s = 128; s > 0; s >>= 1) {
        if (tid < s) red[tid] = fmaxf(red[tid], red[tid + s]);
        __syncthreads();
    }
    const float scale = red[0];
    const float qs = 32638.0f / scale;

    char* d0p = (char*)(ws + (is_r ? AR0_OFF : AZ0_OFF));
    char* d1p = (char*)(ws + (is_r ? AR1_OFF : AZ1_OFF));
    for (int i = tid; i < n; i += 256) {
        const int wq = __float2int_rn(wsrc[i] * qs);
        const int d1 = ((wq + 128) & 255) - 128;
        const int d0 = (wq - d1) >> 8;
        int ci, tap;
        if (is_r) { ci = i; tap = 0; } else { ci = i / 9; tap = i - ci * 9; }
        const int cq = ci >> 6, qq = (ci >> 4) & 3, jj = ci & 15;
        const int addr = is_r
            ? ((co >> 4) * 2048 + cq * 1024 + qq * 256 + (co & 15) * 16 + jj)
            : ((co >> 4) * 18432 + (tap * 2 + cq) * 1024 + qq * 256 + (co & 15) * 16 + jj);
        d0p[addr] = (char)d0;
        d1p[addr] = (char)d1;
    }
    if (tid == 0) {
        float* prm = (float*)(ws + PRM_OFF);
        if (!is_r) {
            const float s1 = g1[co] * (1.0f / sqrtf(v1[co] + BN_EPS));
            prm[co]       = 0.5f * (scale / 32638.0f) * s1;
            prm[256 + co] = 0.5f * (b1[co] - m1[co] * s1);
        } else {
            const float s2 = gr[co] * (1.0f / sqrtf(vr[co] + BN_EPS));
            prm[512 + co] = 0.5f * (scale / 32638.0f) * s2;
            prm[768 + co] = 0.5f * (br[co] - mr[co] * s2);
        }
    }
}

// Stem: conv3x3 (2->128) + BN + LIF, writes packed (byte-swizzled) spikes.
__global__ __launch_bounds__(256) void stem_kernel(
    const float* __restrict__ x, const float* __restrict__ w0,
    const float* __restrict__ g0, const float* __restrict__ b0,
    const float* __restrict__ m0, const float* __restrict__ v0,
    unsigned char* __restrict__ sp)
{
    const int wseg = blockIdx.x;
    const int h    = blockIdx.y;
    const int b    = blockIdx.z;
    const int lane = threadIdx.x & 63;
    const int cg   = threadIdx.x >> 6;
    const int w    = wseg * 64 + lane;

    __shared__ __align__(16) float wl[2560];     // [c][20] (18 used)
    __shared__ float sc0s[128], m0s[128], b0s[128];

    for (int i = threadIdx.x; i < 2304; i += 256) {
        const int c = i / 18, k2 = i - c * 18;
        wl[c * 20 + k2] = w0[i];
    }
    if (threadIdx.x < 128) {
        const int c = threadIdx.x;
        sc0s[c] = g0[c] * (1.0f / sqrtf(v0[c] + BN_EPS));
        m0s[c] = m0[c]; b0s[c] = b0[c];
    }
    __syncthreads();

    float xv[4][2][3][3];
#pragma unroll
    for (int t = 0; t < 4; ++t)
#pragma unroll
        for (int ci = 0; ci < 2; ++ci)
#pragma unroll
            for (int dh = 0; dh < 3; ++dh)
#pragma unroll
                for (int dw = 0; dw < 3; ++dw) {
                    const int hh = h + dh - 1, ww = w + dw - 1;
                    const bool ok = ((unsigned)hh < 128u) && ((unsigned)ww < 128u);
                    xv[t][ci][dh][dw] = ok ? x[(((size_t)(t * 8 + b) * 2 + ci) * 128 + hh) * 128 + ww] : 0.0f;
                }

    const int pix = w + 1;
    const int sw = (pix & 7) << 4;
    unsigned char* dst = sp + ((size_t)b * SP_BSTR) + ((size_t)((h + 1) * 130 + pix)) * 128;
    for (int i = 0; i < 8; ++i) {
        unsigned dwv = 0u;
#pragma unroll
        for (int j = 0; j < 4; ++j) {
            const int c = cg * 32 + i * 4 + j;
            float wreg[18];
            {
                const float4 wa = *(const float4*)&wl[c * 20];
                const float4 wb = *(const float4*)&wl[c * 20 + 4];
                const float4 wc = *(const float4*)&wl[c * 20 + 8];
                const float4 wd = *(const float4*)&wl[c * 20 + 12];
                const float2 we = *(const float2*)&wl[c * 20 + 16];
                wreg[0]=wa.x; wreg[1]=wa.y; wreg[2]=wa.z; wreg[3]=wa.w;
                wreg[4]=wb.x; wreg[5]=wb.y; wreg[6]=wb.z; wreg[7]=wb.w;
                wreg[8]=wc.x; wreg[9]=wc.y; wreg[10]=wc.z; wreg[11]=wc.w;
                wreg[12]=wd.x; wreg[13]=wd.y; wreg[14]=wd.z; wreg[15]=wd.w;
                wreg[16]=we.x; wreg[17]=we.y;
            }
            const float sc = sc0s[c], mm = m0s[c], bb = b0s[c];
            float v = 0.0f; unsigned bits = 0u;
#pragma unroll
            for (int t = 0; t < 4; ++t) {
                float sum = 0.0f;
#pragma unroll
                for (int ci = 0; ci < 2; ++ci)
#pragma unroll
                    for (int dh = 0; dh < 3; ++dh)
#pragma unroll
                        for (int dw = 0; dw < 3; ++dw)
                            sum += xv[t][ci][dh][dw] * wreg[ci * 9 + dh * 3 + dw];
                const float y = (sum - mm) * sc + bb;
                v = v + (y - v) * 0.5f;
                if (v - 1.0f >= 0.0f) { bits |= 1u << t; v = 0.0f; }
            }
            dwv |= bits << (j * 8);
        }
        *(unsigned*)(dst + ((cg * 32 + i * 4) ^ sw)) = dwv;
    }
}

// Main fused: conv3x3(z) + conv1x1(r) via mfma_i32_16x16x64_i8 (2 digits),
// BN + LIF in-lane (pk-fma pairs), full-line staged stores.
// Block = 8 waves: waves 0-3 -> row h0, waves 4-7 -> row h0+1; 16-row strip,
// 8 passes (startup amortized 2x vs round 11). Grid 2048, XCD-swizzled.
__global__ __launch_bounds__(512, 2) void main_i8_2r(
    const unsigned char* __restrict__ ws, float* __restrict__ out)
{
    __shared__ __align__(16) char lds[LDS_TOT];

    const int bid = blockIdx.x;
    const int xcd = bid & 7;
    const int k   = bid >> 3;            // 0..255
    const int sub = k & 31;
    const int sidx = k >> 5;             // 0..7
    const int strip = sidx * 8 + xcd;    // 0..63
    const int coblk = sub >> 1;
    const int wseg  = sub & 1;
    const int hstrip = strip >> 3;       // 0..7 (16 rows each)
    const int b      = strip & 7;

    const int tid  = threadIdx.x;
    const int lane = tid & 63;
    const int wid  = tid >> 6;
    const int rg   = wid >> 2;
    const int ws4  = wid & 3;
    const int q    = lane >> 4;
    const int r16  = lane & 15;
    const int r3   = r16 & 3;
    const int ra   = r16 >> 2;
    const int wbase  = wseg * 64;
    const int hfirst = hstrip * 16;

    const unsigned char* spg = ws + (size_t)b * SP_BSTR + (size_t)wbase * 128;

    // ---- weights: Az digit0 + Ar (both digits) into registers, once ----
    i32x4 a0z[2][9];
#pragma unroll
    for (int cq = 0; cq < 2; ++cq)
#pragma unroll
        for (int tap = 0; tap < 9; ++tap)
            a0z[cq][tap] = *(const i32x4*)(ws + AZ0_OFF + coblk * 18432
                                           + ((tap * 2 + cq) << 10) + lane * 16);
    i32x4 ar0[2], ar1[2];
#pragma unroll
    for (int cq = 0; cq < 2; ++cq) {
        ar0[cq] = *(const i32x4*)(ws + AR0_OFF + coblk * 2048 + (cq << 10) + lane * 16);
        ar1[cq] = *(const i32x4*)(ws + AR1_OFF + coblk * 2048 + (cq << 10) + lane * 16);
    }

    // folded+halved epilogue params per acc register
    const float* prm = (const float*)(ws + PRM_OFF);
    float zmul_[4], zoff_[4], rmul_[4], roff_[4];
#pragma unroll
    for (int reg = 0; reg < 4; ++reg) {
        const int co = coblk * 16 + q * 4 + reg;
        zmul_[reg] = prm[co];       zoff_[reg] = prm[256 + co];
        rmul_[reg] = prm[512 + co]; roff_[reg] = prm[768 + co];
    }

    // ---- stage Az digit1 (18 KB) + ring rows hfirst..hfirst+3 (66-pix) ----
    {
        const uint4* s = (const uint4*)(ws + AZ1_OFF + (size_t)coblk * 18432);
        uint4* d = (uint4*)&lds[LDS_AZ1];
        for (int i = tid; i < 1152; i += 512) d[i] = s[i];
    }
    for (int i = tid; i < 2112; i += 512) {
        const int rr = i / 528;
        const int off = (i - rr * 528) * 16;
        const int gr = hfirst + rr;
        *(uint4*)&lds[LDS_RING + (gr & 3) * RING_ROW + off] =
            *(const uint4*)(spg + (size_t)gr * 16640 + off);
    }
    __syncthreads();

    const int plbase = ws4 * 16 + r16;
    const int co16 = q * 4 + r3;
    const int pq   = ws4 * 4 + ra;
    const int swz  = (co16 & 7) << 1;
    const int stg0 = LDS_STG + ((rg * 4 * 16 + co16) * 16 + (pq ^ swz)) * 4;

    for (int p = 0; p < 8; ++p) {
        const int h0 = hfirst + 2 * p;
        const int my_row = h0 + rg;

        // prefetch next 2 sp rows (gr = h0+4, h0+5) into registers
        uint4 pfa0, pfa1, pfb0, pfb1;
        if (p < 7) {
            const unsigned char* s0 = spg + (size_t)(h0 + 4) * 16640;
            const unsigned char* s1 = spg + (size_t)(h0 + 5) * 16640;
            pfa0 = *(const uint4*)(s0 + tid * 16);
            pfb0 = *(const uint4*)(s1 + tid * 16);
            if (tid < 16) {
                pfa1 = *(const uint4*)(s0 + (tid + 512) * 16);
                pfb1 = *(const uint4*)(s1 + (tid + 512) * 16);
            }
        }

        i32x4 z0[4], z1[4], r0a[4], r1a[4];
#pragma unroll
        for (int t = 0; t < 4; ++t) {
            z0[t] = (i32x4)(0); z1[t] = (i32x4)(0);
            r0a[t] = (i32x4)(0); r1a[t] = (i32x4)(0);
        }

        __builtin_amdgcn_s_setprio(1);
#pragma unroll
        for (int cq = 0; cq < 2; ++cq) {
#pragma unroll
            for (int kw = 0; kw < 3; ++kw) {
                i32x4 a1[3];
#pragma unroll
                for (int kh = 0; kh < 3; ++kh)
                    a1[kh] = *(const i32x4*)&lds[LDS_AZ1 + (((kh * 3 + kw) * 2 + cq) << 10)
                                                 + lane * 16];
                const int pl = plbase + kw;
                const int addrb = pl * 128 + ((cq * 64 + q * 16) ^ ((pl & 7) << 4));
#pragma unroll
                for (int rr = 0; rr < 3; ++rr) {
                    const int slot = (my_row + rr) & 3;
                    const uint4 dd = *(const uint4*)&lds[LDS_RING + slot * RING_ROW + addrb];
#pragma unroll
                    for (int t = 0; t < 4; ++t) {
                        const unsigned Mt = 0x01010101u << t;   // single-AND decode
                        i32x4 bt;
                        bt[0] = (int)(dd.x & Mt);
                        bt[1] = (int)(dd.y & Mt);
                        bt[2] = (int)(dd.z & Mt);
                        bt[3] = (int)(dd.w & Mt);
                        MFI8(z0[t], a0z[cq][rr * 3 + kw], bt);
                        MFI8(z1[t], a1[rr], bt);
                        if (kw == 1 && rr == 1) {
                            MFI8(r0a[t], ar0[cq], bt);
                            MFI8(r1a[t], ar1[cq], bt);
                        }
                    }
                }
            }
        }
        __builtin_amdgcn_s_setprio(0);

        // Epilogue: combine digits (exact 2^-t shift), BN + LIF as pk-fma
        // pairs (v' = fma(v, 0.5, 0.5*y), IEEE fma -> bit-identical), pack
        unsigned pack[4] = {0u, 0u, 0u, 0u};
#pragma unroll
        for (int pr = 0; pr < 2; ++pr) {
            const int ra0 = pr * 2, ra1 = pr * 2 + 1;
            f32x2 vz = {0.0f, 0.0f}, vr2 = {0.0f, 0.0f};
#pragma unroll
            for (int t = 0; t < 4; ++t) {
                const int zi0 = (z0[t][ra0] * 256 + z1[t][ra0]) >> t;
                const int zi1 = (z0[t][ra1] * 256 + z1[t][ra1]) >> t;
                f32x2 yzh;
                yzh.x = fmaf((float)zi0, zmul_[ra0], zoff_[ra0]);
                yzh.y = fmaf((float)zi1, zmul_[ra1], zoff_[ra1]);
                vz = __builtin_elementwise_fma(vz, (f32x2){0.5f, 0.5f}, yzh);
                const int ri0 = (r0a[t][ra0] * 256 + r1a[t][ra0]) >> t;
                const int ri1 = (r0a[t][ra1] * 256 + r1a[t][ra1]) >> t;
                f32x2 yrh;
                yrh.x = fmaf((float)ri0, rmul_[ra0], roff_[ra0]);
                yrh.y = fmaf((float)ri1, rmul_[ra1], roff_[ra1]);
                vr2 = __builtin_elementwise_fma(vr2, (f32x2){0.5f, 0.5f}, yrh);

                unsigned v0b = 0u, v1b = 0u;
                if (vz.x >= 1.0f) { v0b = 1u; vz.x = 0.0f; }
                if (vr2.x >= 1.0f) { v0b += 1u; vr2.x = 0.0f; }
                if (vz.y >= 1.0f) { v1b = 1u; vz.y = 0.0f; }
                if (vr2.y >= 1.0f) { v1b += 1u; vr2.y = 0.0f; }
                pack[t] |= (v0b << (ra0 * 8)) | (v1b << (ra1 * 8));
            }
        }

        // in-wave 4x4 byte transpose across r3 lanes: co-major -> pixel-major
#pragma unroll
        for (int t = 0; t < 4; ++t) {
            unsigned u = pack[t];
            unsigned pt = __shfl_xor(u, 1);
            u = (r3 & 1) ? ((u & 0xFF00FF00u) | ((pt >> 8) & 0x00FF00FFu))
                         : ((u & 0x00FF00FFu) | ((pt << 8) & 0xFF00FF00u));
            pt = __shfl_xor(u, 2);
            u = (r3 & 2) ? ((u & 0xFFFF0000u) | (pt >> 16))
                         : ((u & 0x0000FFFFu) | (pt << 16));
            pack[t] = u;
        }

        __syncthreads();   // bar1: ring + stg reads done

        if (p < 7) {       // commit prefetched rows into retired slots
            char* dA = &lds[LDS_RING + ((h0 + 4) & 3) * RING_ROW];
            char* dB = &lds[LDS_RING + ((h0 + 5) & 3) * RING_ROW];
            *(uint4*)(dA + tid * 16) = pfa0;
            *(uint4*)(dB + tid * 16) = pfb0;
            if (tid < 16) {
                *(uint4*)(dA + (tid + 512) * 16) = pfa1;
                *(uint4*)(dB + (tid + 512) * 16) = pfb1;
            }
        }
#pragma unroll
        for (int t = 0; t < 4; ++t)
            *(unsigned*)&lds[stg0 + t * 1024] = pack[t];
        __syncthreads();   // bar2: staged bytes + new ring rows visible

        // full-line stores: 16 consecutive lanes cover one 256-B row chunk
#pragma unroll
        for (int it = 0; it < 4; ++it) {
            const int u = it * 512 + tid;
            const int q4  = u & 15;
            const int cs  = (u >> 4) & 15;
            const int tt  = (u >> 8) & 3;
            const int rg2 = u >> 10;
            const unsigned dv = *(const unsigned*)
                &lds[LDS_STG + (((rg2 * 4 + tt) * 16 + cs) * 16 + (q4 ^ ((cs & 7) << 1))) * 4];
            f32x4 f;
            f[0] = (float)(dv & 0xffu);
            f[1] = (float)((dv >> 8) & 0xffu);
            f[2] = (float)((dv >> 16) & 0xffu);
            f[3] = (float)((dv >> 24) & 0xffu);
            float* op = out + (((size_t)(tt * 8 + b) * 256 + coblk * 16 + cs) << 14)
                            + (h0 + rg2) * 128 + wbase + q4 * 4;
            *(f32x4*)op = f;
        }
    }
}

extern "C" void kernel_launch(void* const* d_in, const int* in_sizes, int n_in,
                              void* d_out, int out_size, void* d_ws, size_t ws_size,
                              hipStream_t stream) {
    const float* x  = (const float*)d_in[0];
    const float* w0 = (const float*)d_in[1];
    const float* g0 = (const float*)d_in[2];
    const float* b0 = (const float*)d_in[3];
    const float* m0 = (const float*)d_in[4];
    const float* v0 = (const float*)d_in[5];
    const float* w1 = (const float*)d_in[6];
    const float* g1 = (const float*)d_in[7];
    const float* b1 = (const float*)d_in[8];
    const float* m1 = (const float*)d_in[9];
    const float* v1 = (const float*)d_in[10];
    const float* wr = (const float*)d_in[11];
    const float* gr = (const float*)d_in[12];
    const float* br = (const float*)d_in[13];
    const float* mr = (const float*)d_in[14];
    const float* vr = (const float*)d_in[15];

    unsigned char* ws = (unsigned char*)d_ws;

    zero_halo_kernel<<<dim3(129), dim3(256), 0, stream>>>(ws);
    prep_kernel<<<dim3(512), dim3(256), 0, stream>>>(w1, wr, g1, v1, b1, m1, gr, vr, br, mr, ws);
    stem_kernel<<<dim3(2, 128, 8), dim3(256), 0, stream>>>(x, w0, g0, b0, m0, v0, ws);
    main_i8_2r<<<dim3(2048), dim3(512), 0, stream>>>(ws, (float*)d_out);
}